// Round 7
// baseline (478.277 us; speedup 1.0000x reference)
//
#include <hip/hip_runtime.h>
#include <hip/hip_bf16.h>

// B=4, T=1024, E=1024, H=16, D=64, P=257.  Slot s = b*16+h (64 slots).
// Quirk: score slot m uses rel-K of slot pm=(m&15)*4+(m>>4); attn of slot m
// feeds w2 output of slot m2=(m&3)*16+(m>>2).
// R22: k_fused Q-tile 32->16 rows/block (grid 2048->4096).  Total work
// invariant (all phases scale with rows); per-block LDS 35.3->17.4 KB and
// VGPR state halves -> residency ~2.25 -> ~6 blocks/CU (launch_bounds(256,6)
// caps VGPR at 85; R21 build used 84 with double state).  Latency-bound
// diagnosis: R20 FETCH/4.5 flat, R21 VALU -7pp flat, floors ~14us vs 123us.
// R21: log2-domain softmax (Q pre-scaled 0.125*log2e), med3 jd clamp.
// R20: XCD swizzle.  R18/19: k_sum + qkv-clone k_gemm_o.  R16: qkv 128x128.

typedef __attribute__((ext_vector_type(8))) short short8;
typedef __attribute__((ext_vector_type(4))) float f32x4;

__device__ __forceinline__ float bf16f(unsigned int u) {
    union { unsigned int i; float f; } v; v.i = u << 16; return v.f;
}
__device__ __forceinline__ unsigned short f2b(float x) {
    __hip_bfloat16 h = __float2bfloat16(x);
    return *reinterpret_cast<unsigned short*>(&h);
}
__device__ __forceinline__ void gl_lds16(const unsigned short* g, unsigned short* l) {
    __builtin_amdgcn_global_load_lds(
        (const __attribute__((address_space(1))) void*)g,
        (__attribute__((address_space(3))) void*)l, 16, 0, 0);
}

// ---------------------------------------------------------------------------
// K0: prep.  z=0..4: split fp32 -> (hi,lo) bf16.  z=5: rel tables.
// lo halves skipped for Wq/Wk/Wv (z=1..3) - never read.
// ---------------------------------------------------------------------------
__global__ __launch_bounds__(256) void k_prep(
    const float* __restrict__ hs, const float* __restrict__ Wq,
    const float* __restrict__ Wk, const float* __restrict__ Wv,
    const float* __restrict__ Wo, const float* __restrict__ relk,
    const float* __restrict__ relv,
    unsigned short* __restrict__ hh, unsigned short* __restrict__ hl,
    unsigned short* __restrict__ wqh, unsigned short* __restrict__ wql,
    unsigned short* __restrict__ wkh, unsigned short* __restrict__ wkl,
    unsigned short* __restrict__ wvh, unsigned short* __restrict__ wvl,
    unsigned short* __restrict__ woh, unsigned short* __restrict__ wol,
    unsigned short* __restrict__ relkB, unsigned short* __restrict__ relvT)
{
    const int z = blockIdx.y;
    const int tid = threadIdx.x;
    if (z < 5) {
        const float* src = (z == 0) ? hs : (z == 1) ? Wq : (z == 2) ? Wk
                         : (z == 3) ? Wv : Wo;
        unsigned short* hi = (z == 0) ? hh : (z == 1) ? wqh : (z == 2) ? wkh
                           : (z == 3) ? wvh : woh;
        unsigned short* lo = (z == 0) ? hl : (z == 1) ? wql : (z == 2) ? wkl
                           : (z == 3) ? wvl : wol;
        const bool wlo = (z == 0) || (z == 4);
        const int n4 = (z == 0) ? 1048576 : 262144;
        const int stride = gridDim.x * 256;
        for (int i = blockIdx.x * 256 + tid; i < n4; i += stride) {
            float4 x = *(const float4*)(src + i*4);
            unsigned short h[4], l[4];
            float xs[4] = {x.x, x.y, x.z, x.w};
            #pragma unroll
            for (int j = 0; j < 4; ++j) {
                h[j] = f2b(xs[j]);
                l[j] = f2b(xs[j] - bf16f(h[j]));
            }
            *(ushort4*)(hi + i*4) = make_ushort4(h[0], h[1], h[2], h[3]);
            if (wlo)
                *(ushort4*)(lo + i*4) = make_ushort4(l[0], l[1], l[2], l[3]);
        }
    } else if (blockIdx.x == 0) {
        for (int i = tid; i < 272*64; i += 256) {
            int j = i >> 6;
            relkB[i] = (j < 257) ? f2b(relk[i]) : (unsigned short)0;
        }
        int d = tid >> 2, grp = tid & 3;
        for (int jj = 0; jj < 66; ++jj) {
            int j = grp*66 + jj;
            if (j < 264)
                relvT[d*264 + j] = (j < 257) ? f2b(relv[j*64 + d]) : (unsigned short)0;
        }
    }
}

// ---------------------------------------------------------------------------
// K1: QKV projection, 128x128 tile, double-buffered async staging, 2-MFMA
// split (AhBh + AlBh).  Grid (8, 32, 3) = 768 blocks = 3/CU, LDS 48 KB.
// R21: z==0 scale folds log2e (Q in log2 domain for k_fused's exp2).
// ---------------------------------------------------------------------------
__global__ __launch_bounds__(256, 3) void k_gemm_qkv(
    const unsigned short* __restrict__ hh, const unsigned short* __restrict__ hl,
    const unsigned short* __restrict__ wqh, const unsigned short* __restrict__ wkh,
    const unsigned short* __restrict__ wvh,
    const float* __restrict__ bq, const float* __restrict__ bk,
    const float* __restrict__ bv,
    unsigned short* __restrict__ qb, unsigned short* __restrict__ kb,
    unsigned short* __restrict__ vt)
{
    __shared__ __align__(16) unsigned short sAh[2][128][32];
    __shared__ __align__(16) unsigned short sAl[2][128][32];
    __shared__ __align__(16) unsigned short sBh[2][128][32];
    const int tid = threadIdx.x;
    // XCD-aware remap: d = hw linear id (768 = 8*96, bijective)
    const int d_ = blockIdx.x + (blockIdx.y << 3) + (blockIdx.z << 8);
    const int l_ = (d_ & 7) * 96 + (d_ >> 3);
    const int nbb = l_ / 24;
    const int r24 = l_ - nbb * 24;
    const int z   = r24 >> 3;
    const int ebb = r24 & 7;
    const int eb = ebb * 128, nb = nbb * 128;
    const unsigned short* Bh = (z == 0) ? wqh : (z == 1) ? wkh : wvh;
    const float* bias = (z == 0) ? bq : (z == 1) ? bk : bv;
    const float scale = (z == 0) ? 0.125f * 1.44269504f : 1.0f;
    const int w = tid >> 6, lane = tid & 63, lq = lane & 15, quad = lane >> 4;
    const int wr = w >> 1, wc = w & 1;

    const int prow = lane >> 2;
    const int pc8  = ((((lane & 3) - ((lane >> 3) & 3)) & 3)) * 8;
    const int arow = nb + w*16 + prow;
    const int brow = eb + w*16 + prow;

    f32x4 acc[4][4];
    #pragma unroll
    for (int i = 0; i < 4; ++i)
        #pragma unroll
        for (int j = 0; j < 4; ++j) acc[i][j] = (f32x4){0,0,0,0};

    const int pcol = ((quad + (lq >> 1)) & 3) * 8;   // swizzled frag column

    {
        gl_lds16(hh + (size_t)arow * 1024 + pc8,        &sAh[0][w*16][0]);
        gl_lds16(hh + (size_t)(arow + 64) * 1024 + pc8, &sAh[0][64 + w*16][0]);
        gl_lds16(hl + (size_t)arow * 1024 + pc8,        &sAl[0][w*16][0]);
        gl_lds16(hl + (size_t)(arow + 64) * 1024 + pc8, &sAl[0][64 + w*16][0]);
        gl_lds16(Bh + (size_t)brow * 1024 + pc8,        &sBh[0][w*16][0]);
        gl_lds16(Bh + (size_t)(brow + 64) * 1024 + pc8, &sBh[0][64 + w*16][0]);
    }

    for (int k0 = 0; k0 < 1024; k0 += 32) {
        const int cur = (k0 >> 5) & 1;
        __syncthreads();
        if (k0 < 992) {
            const int kn = k0 + 32, nxt = 1 - cur;
            gl_lds16(hh + (size_t)arow * 1024 + kn + pc8,        &sAh[nxt][w*16][0]);
            gl_lds16(hh + (size_t)(arow + 64) * 1024 + kn + pc8, &sAh[nxt][64 + w*16][0]);
            gl_lds16(hl + (size_t)arow * 1024 + kn + pc8,        &sAl[nxt][w*16][0]);
            gl_lds16(hl + (size_t)(arow + 64) * 1024 + kn + pc8, &sAl[nxt][64 + w*16][0]);
            gl_lds16(Bh + (size_t)brow * 1024 + kn + pc8,        &sBh[nxt][w*16][0]);
            gl_lds16(Bh + (size_t)(brow + 64) * 1024 + kn + pc8, &sBh[nxt][64 + w*16][0]);
        }

        short8 ah[4], al[4], bh4[4];
        #pragma unroll
        for (int t = 0; t < 4; ++t) {
            ah[t] = *(const short8*)&sAh[cur][wr*64 + t*16 + lq][pcol];
            al[t] = *(const short8*)&sAl[cur][wr*64 + t*16 + lq][pcol];
        }
        #pragma unroll
        for (int t = 0; t < 4; ++t)
            bh4[t] = *(const short8*)&sBh[cur][wc*64 + t*16 + lq][pcol];
        #pragma unroll
        for (int ti = 0; ti < 4; ++ti)
            #pragma unroll
            for (int tj = 0; tj < 4; ++tj) {
                acc[ti][tj] = __builtin_amdgcn_mfma_f32_16x16x32_bf16(ah[ti], bh4[tj], acc[ti][tj], 0, 0, 0);
                acc[ti][tj] = __builtin_amdgcn_mfma_f32_16x16x32_bf16(al[ti], bh4[tj], acc[ti][tj], 0, 0, 0);
            }
    }

    #pragma unroll
    for (int tj = 0; tj < 4; ++tj) {
        int e = eb + wc*64 + tj*16 + lq;
        float bb = bias[e];
        int h = e >> 6, d = e & 63;
        #pragma unroll
        for (int ti = 0; ti < 4; ++ti) {
            #pragma unroll
            for (int i = 0; i < 4; ++i) {
                int n = nb + wr*64 + ti*16 + quad*4 + i;
                int bidx = n >> 10, t = n & 1023;
                int s = bidx*16 + h;
                float val = (acc[ti][tj][i] + bb) * scale;
                if (z == 2)
                    vt[(((size_t)(s*64 + d)) << 10) + t] = f2b(val);
                else if (z == 0)
                    qb[(((size_t)(s*1024 + t)) << 6) + d] = f2b(val);
                else
                    kb[(((size_t)(s*1024 + t)) << 6) + d] = f2b(val);
            }
        }
    }
}

// ---------------------------------------------------------------------------
// K2: MFMA flash attention.  R22: 16 Q-rows/block, LDS 17.4 KB, ~6 blocks/CU.
// R21: log2-domain softmax + med3 jd clamp.  R20: XCD swizzle (64 same-m
// blocks per XCD group, K/V L2-resident).
// ---------------------------------------------------------------------------
__global__ __launch_bounds__(256, 6) void k_fused(
    const unsigned short* __restrict__ qb, const unsigned short* __restrict__ kb,
    const unsigned short* __restrict__ vt, const unsigned short* __restrict__ relkB,
    const unsigned short* __restrict__ relvT, const float* __restrict__ relv,
    float* __restrict__ c1, float* __restrict__ c2)
{
    __shared__ __align__(16) unsigned short sP[2][16][72];
    __shared__ __align__(16) unsigned short sG[16][104];
    __shared__ unsigned short sR[16][273];
    __shared__ float sRed[4][3][16];

    const int tid = threadIdx.x;
    // XCD-aware remap: 4096 blocks = 8 * 512, bijective
    const int d_ = blockIdx.x + (blockIdx.y << 6);
    const int l_ = (d_ & 7) * 512 + (d_ >> 3);
    const int m  = l_ >> 6;
    const int q0 = (l_ & 63) * 16;
    const int pm = (m & 15) * 4 + (m >> 4);
    const int m2 = (m & 3) * 16 + (m >> 2);
    const int w    = tid >> 6;
    const int lane = tid & 63;
    const int lq   = lane & 15;
    const int quad = lane >> 4;

    // sR fill: rows q0..q0+15 of slot pm vs all rel-K columns
    {
        const unsigned short* qpm = qb + (((size_t)(pm*1024 + q0 + lq)) << 6);
        short8 a0 = *(const short8*)(qpm + quad*8);
        short8 a1 = *(const short8*)(qpm + 32 + quad*8);
        for (int jt = w; jt < 17; jt += 4) {
            const unsigned short* rkb = relkB + (size_t)(jt*16 + lq) * 64;
            short8 b0 = *(const short8*)(rkb + quad*8);
            short8 b1 = *(const short8*)(rkb + 32 + quad*8);
            f32x4 cr = {0,0,0,0};
            cr = __builtin_amdgcn_mfma_f32_16x16x32_bf16(a0, b0, cr, 0, 0, 0);
            cr = __builtin_amdgcn_mfma_f32_16x16x32_bf16(a1, b1, cr, 0, 0, 0);
            #pragma unroll
            for (int i = 0; i < 4; ++i)
                sR[quad*4 + i][jt*16 + lq] = f2b(cr[i]);
        }
    }
    __syncthreads();

    short8 aq0, aq1;
    {
        const unsigned short* qm = qb + (((size_t)(m*1024 + q0 + lq)) << 6);
        aq0 = *(const short8*)(qm + quad*8);
        aq1 = *(const short8*)(qm + 32 + quad*8);
    }
    const float relE0 = relv[w*16 + lq];
    const float relE1 = relv[256*64 + w*16 + lq];

    float lsum[4], slow[4], shigh[4];
    f32x4 c1a = (f32x4){0,0,0,0}, c2a = (f32x4){0,0,0,0};
    #pragma unroll
    for (int i = 0; i < 4; ++i) { lsum[i] = 0.0f; slow[i] = 0.0f; shigh[i] = 0.0f; }

    const unsigned short* kbase = kb + (((size_t)(m*1024 + w*16 + lq)) << 6);
    const unsigned short* vbase = vt + (((size_t)(m*64 + w*16 + lq)) << 10);
    short8 ck0 = *(const short8*)(kbase + quad*8);
    short8 ck1 = *(const short8*)(kbase + 32 + quad*8);
    short8 cv0 = *(const short8*)(vbase + quad*8);
    short8 cv1 = *(const short8*)(vbase + 32 + quad*8);

    // jd = clamp(jbase + row - 64*kt, 0, 256), row = quad*4+i
    const int jbase = q0 + 128 - (w*16 + lq);

    #pragma unroll 1
    for (int kt = 0; kt < 16; ++kt) {
        const int k0 = kt * 64;
        const int dmin = q0 - k0 - 63;
        const int dmax = q0 + 15 - k0;
        const bool needG = (dmax >= -127) && (dmin <= 127);
        const int buf = kt & 1;
        const int jb = jbase - k0;

        short8 nk0 = ck0, nk1 = ck1, nv0 = cv0, nv1 = cv1;
        if (kt < 15) {
            const size_t ko = (size_t)(k0 + 64);
            nk0 = *(const short8*)(kbase + (ko << 6) + quad*8);
            nk1 = *(const short8*)(kbase + (ko << 6) + 32 + quad*8);
            nv0 = *(const short8*)(vbase + ko + quad*8);
            nv1 = *(const short8*)(vbase + ko + 32 + quad*8);
        }

        f32x4 s4 = (f32x4){0,0,0,0};
        s4 = __builtin_amdgcn_mfma_f32_16x16x32_bf16(aq0, ck0, s4, 0, 0, 0);
        s4 = __builtin_amdgcn_mfma_f32_16x16x32_bf16(aq1, ck1, s4, 0, 0, 0);

        float e[4];
        #pragma unroll
        for (int i = 0; i < 4; ++i) {
            int row = quad*4 + i;
            int jd = jb + row;
            jd = jd < 0 ? 0 : jd;
            jd = jd > 256 ? 256 : jd;
            float ev = exp2f(s4[i] + bf16f(sR[row][jd]));
            e[i] = ev;
            lsum[i] += ev;
            if (jd == 0)        slow[i]  += ev;
            else if (jd == 256) shigh[i] += ev;
            sP[buf][quad*4 + i][w*16 + lq] = f2b(ev);
        }
        if (needG) {
            #pragma unroll
            for (int i = 0; i < 4; ++i) {
                int idx = tid + i * 256;
                if (idx < 832) ((unsigned int*)sG)[idx] = 0u;
            }
        }
        __syncthreads();

        if (needG) {
            int jminb = q0 - k0 - 63;
            jminb = (jminb < -127 ? -127 : jminb) + 128;
            int jlo8 = jminb & ~7;
            if (jlo8 > 160) jlo8 = 160;
            #pragma unroll
            for (int i = 0; i < 4; ++i) {
                int row = quad*4 + i;
                int jd = jb + row;   // interior: equals clamped jd
                if (jd > 0 && jd < 256)
                    sG[quad*4 + i][jd - jlo8] = f2b(e[i]);
            }
        }

        {
            short8 ap0 = *(const short8*)&sP[buf][lq][quad*8];
            short8 ap1 = *(const short8*)&sP[buf][lq][32 + quad*8];
            c1a = __builtin_amdgcn_mfma_f32_16x16x32_bf16(ap0, cv0, c1a, 0, 0, 0);
            c1a = __builtin_amdgcn_mfma_f32_16x16x32_bf16(ap1, cv1, c1a, 0, 0, 0);
        }

        if (needG) {
            __syncthreads();
            int jminb = q0 - k0 - 63;
            jminb = (jminb < -127 ? -127 : jminb) + 128;
            int jlo8 = jminb & ~7;
            if (jlo8 > 160) jlo8 = 160;
            short8 ag0 = *(const short8*)&sG[lq][quad*8];
            short8 ag1 = *(const short8*)&sG[lq][32 + quad*8];
            short8 ag2 = *(const short8*)&sG[lq][64 + quad*8];
            const unsigned short* rrow = relvT + (size_t)(w*16 + lq) * 264 + jlo8;
            short8 br0 = *(const short8*)(rrow + quad*8);
            short8 br1 = *(const short8*)(rrow + 32 + quad*8);
            short8 br2 = *(const short8*)(rrow + 64 + quad*8);
            c2a = __builtin_amdgcn_mfma_f32_16x16x32_bf16(ag0, br0, c2a, 0, 0, 0);
            c2a = __builtin_amdgcn_mfma_f32_16x16x32_bf16(ag1, br1, c2a, 0, 0, 0);
            c2a = __builtin_amdgcn_mfma_f32_16x16x32_bf16(ag2, br2, c2a, 0, 0, 0);
            __syncthreads();
        }

        ck0 = nk0; ck1 = nk1; cv0 = nv0; cv1 = nv1;
    }

    #pragma unroll
    for (int off = 1; off < 16; off <<= 1) {
        #pragma unroll
        for (int i = 0; i < 4; ++i) {
            lsum[i]  += __shfl_xor(lsum[i],  off, 64);
            slow[i]  += __shfl_xor(slow[i],  off, 64);
            shigh[i] += __shfl_xor(shigh[i], off, 64);
        }
    }
    if (lq == 0) {
        #pragma unroll
        for (int i = 0; i < 4; ++i) {
            int row = quad*4 + i;
            sRed[w][0][row] = lsum[i];
            sRed[w][1][row] = slow[i];
            sRed[w][2][row] = shigh[i];
        }
    }
    __syncthreads();

    const int b1 = m >> 4,  h1 = m & 15;
    const int b2 = m2 >> 4, h2 = m2 & 15;
    #pragma unroll
    for (int i = 0; i < 4; ++i) {
        int row = quad*4 + i;
        float lt = sRed[0][0][row] + sRed[1][0][row] + sRed[2][0][row] + sRed[3][0][row];
        float sl = sRed[0][1][row] + sRed[1][1][row] + sRed[2][1][row] + sRed[3][1][row];
        float sh = sRed[0][2][row] + sRed[1][2][row] + sRed[2][2][row] + sRed[3][2][row];
        float c2v = c2a[i] + sl * relE0 + sh * relE1;
        float inv = 1.0f / lt;
        int col = w*16 + lq;
        c1[(size_t)(b1*1024 + q0 + row) * 1024 + h1*64 + col] = c1a[i] * inv;
        c2[(size_t)(b2*1024 + q0 + row) * 1024 + h2*64 + col] = c2v * inv;
    }
}

// ---------------------------------------------------------------------------
// K2b: A = c1+c2 -> bf16 (hi,lo) split, written into the dead hh/hl buffers.
// ---------------------------------------------------------------------------
__global__ __launch_bounds__(256) void k_sum(
    const float* __restrict__ c1, const float* __restrict__ c2,
    unsigned short* __restrict__ ah, unsigned short* __restrict__ al)
{
    const int stride = gridDim.x * 256;
    for (int i = blockIdx.x * 256 + threadIdx.x; i < 1048576; i += stride) {
        float4 a = *(const float4*)(c1 + i*4);
        float4 b = *(const float4*)(c2 + i*4);
        float s[4] = {a.x+b.x, a.y+b.y, a.z+b.z, a.w+b.w};
        unsigned short h[4], l[4];
        #pragma unroll
        for (int j = 0; j < 4; ++j) {
            h[j] = f2b(s[j]);
            l[j] = f2b(s[j] - bf16f(h[j]));
        }
        *(ushort4*)(ah + i*4) = make_ushort4(h[0], h[1], h[2], h[3]);
        *(ushort4*)(al + i*4) = make_ushort4(l[0], l[1], l[2], l[3]);
    }
}

// ---------------------------------------------------------------------------
// K3: out = A @ Wo^T + bo with A = pre-split (c1+c2) hi/lo.  qkv-clone:
// 128x64 tile, cross-iteration async dbuf staging, 3-MFMA (AhBh+AlBh+AhBl).
// Grid (16,32) = 512 blocks, LDS 48 KB.  R20: XCD swizzle, same-nb (16
// eb-blocks, shared A-panel) contiguous per XCD.
// ---------------------------------------------------------------------------
__global__ __launch_bounds__(256, 3) void k_gemm_o(
    const unsigned short* __restrict__ ah_, const unsigned short* __restrict__ al_,
    const unsigned short* __restrict__ woh, const unsigned short* __restrict__ wol,
    const float* __restrict__ bo, float* __restrict__ outp)
{
    __shared__ __align__(16) unsigned short sAh[2][128][32];
    __shared__ __align__(16) unsigned short sAl[2][128][32];
    __shared__ __align__(16) unsigned short sBh[2][64][32];
    __shared__ __align__(16) unsigned short sBl[2][64][32];
    const int tid = threadIdx.x;
    // XCD-aware remap: 512 blocks = 8 * 64, bijective
    const int d_ = blockIdx.x + (blockIdx.y << 4);
    const int l_ = (d_ & 7) * 64 + (d_ >> 3);
    const int eb = (l_ & 15) * 64, nb = (l_ >> 4) * 128;
    const int w = tid >> 6, lane = tid & 63, lq = lane & 15, quad = lane >> 4;
    const int wr = w >> 1, wc = w & 1;

    const int prow = lane >> 2;
    const int pc8  = ((((lane & 3) - ((lane >> 3) & 3)) & 3)) * 8;
    const int arow = nb + w*16 + prow;
    const int brow = eb + w*16 + prow;

    f32x4 acc[4][2];
    #pragma unroll
    for (int i = 0; i < 4; ++i)
        #pragma unroll
        for (int j = 0; j < 2; ++j) acc[i][j] = (f32x4){0,0,0,0};

    const int pcol = ((quad + (lq >> 1)) & 3) * 8;

    // prologue: stage tile 0 into buf 0
    {
        gl_lds16(ah_ + (size_t)arow * 1024 + pc8,        &sAh[0][w*16][0]);
        gl_lds16(ah_ + (size_t)(arow + 64) * 1024 + pc8, &sAh[0][64 + w*16][0]);
        gl_lds16(al_ + (size_t)arow * 1024 + pc8,        &sAl[0][w*16][0]);
        gl_lds16(al_ + (size_t)(arow + 64) * 1024 + pc8, &sAl[0][64 + w*16][0]);
        gl_lds16(woh + (size_t)brow * 1024 + pc8,        &sBh[0][w*16][0]);
        gl_lds16(wol + (size_t)brow * 1024 + pc8,        &sBl[0][w*16][0]);
    }

    for (int k0 = 0; k0 < 1024; k0 += 32) {
        const int cur = (k0 >> 5) & 1;
        __syncthreads();
        if (k0 < 992) {
            const int kn = k0 + 32, nxt = 1 - cur;
            gl_lds16(ah_ + (size_t)arow * 1024 + kn + pc8,        &sAh[nxt][w*16][0]);
            gl_lds16(ah_ + (size_t)(arow + 64) * 1024 + kn + pc8, &sAh[nxt][64 + w*16][0]);
            gl_lds16(al_ + (size_t)arow * 1024 + kn + pc8,        &sAl[nxt][w*16][0]);
            gl_lds16(al_ + (size_t)(arow + 64) * 1024 + kn + pc8, &sAl[nxt][64 + w*16][0]);
            gl_lds16(woh + (size_t)brow * 1024 + kn + pc8,        &sBh[nxt][w*16][0]);
            gl_lds16(wol + (size_t)brow * 1024 + kn + pc8,        &sBl[nxt][w*16][0]);
        }

        short8 ah[4], al[4], bhf[2], blf[2];
        #pragma unroll
        for (int t = 0; t < 4; ++t) {
            ah[t] = *(const short8*)&sAh[cur][wr*64 + t*16 + lq][pcol];
            al[t] = *(const short8*)&sAl[cur][wr*64 + t*16 + lq][pcol];
        }
        #pragma unroll
        for (int t = 0; t < 2; ++t) {
            bhf[t] = *(const short8*)&sBh[cur][wc*32 + t*16 + lq][pcol];
            blf[t] = *(const short8*)&sBl[cur][wc*32 + t*16 + lq][pcol];
        }
        #pragma unroll
        for (int ti = 0; ti < 4; ++ti)
            #pragma unroll
            for (int tj = 0; tj < 2; ++tj) {
                acc[ti][tj] = __builtin_amdgcn_mfma_f32_16x16x32_bf16(ah[ti], bhf[tj], acc[ti][tj], 0, 0, 0);
                acc[ti][tj] = __builtin_amdgcn_mfma_f32_16x16x32_bf16(al[ti], bhf[tj], acc[ti][tj], 0, 0, 0);
                acc[ti][tj] = __builtin_amdgcn_mfma_f32_16x16x32_bf16(ah[ti], blf[tj], acc[ti][tj], 0, 0, 0);
            }
    }

    #pragma unroll
    for (int tj = 0; tj < 2; ++tj) {
        int e = eb + wc*32 + tj*16 + lq;
        float bb = bo[e];
        #pragma unroll
        for (int ti = 0; ti < 4; ++ti) {
            #pragma unroll
            for (int i = 0; i < 4; ++i) {
                int n = nb + wr*64 + ti*16 + quad*4 + i;
                outp[(size_t)n * 1024 + e] = acc[ti][tj][i] + bb;
            }
        }
    }
}

// ---------------------------------------------------------------------------
extern "C" void kernel_launch(void* const* d_in, const int* in_sizes, int n_in,
                              void* d_out, int out_size, void* d_ws, size_t ws_size,
                              hipStream_t stream) {
    const float* hs   = (const float*)d_in[0];
    const float* Wq   = (const float*)d_in[1];
    const float* bq   = (const float*)d_in[2];
    const float* Wk   = (const float*)d_in[3];
    const float* bk   = (const float*)d_in[4];
    const float* Wv   = (const float*)d_in[5];
    const float* bv   = (const float*)d_in[6];
    const float* Wo   = (const float*)d_in[7];
    const float* bo   = (const float*)d_in[8];
    const float* relk = (const float*)d_in[9];
    const float* relv = (const float*)d_in[10];
    float* out = (float*)d_out;

    unsigned short* wsu = (unsigned short*)d_ws;
    unsigned short* qbp   = wsu;
    unsigned short* kbp   = wsu + 4194304;
    unsigned short* vtp   = wsu + 8388608;
    unsigned short* relkB = wsu + 12582912;
    unsigned short* relvT = wsu + 12600320;
    float* c1 = (float*)(wsu + 12617360);
    float* c2 = c1 + 4194304;
    unsigned short* hh  = wsu + 29394576;
    unsigned short* hl  = hh + 4194304;
    unsigned short* wqh = hl + 4194304;
    unsigned short* wql = wqh + 1048576;
    unsigned short* wkh = wql + 1048576;
    unsigned short* wkl = wkh + 1048576;
    unsigned short* wvh = wkl + 1048576;
    unsigned short* wvl = wvh + 1048576;
    unsigned short* woh = wvl + 1048576;
    unsigned short* wol = woh + 1048576;

    k_prep<<<dim3(512, 6), 256, 0, stream>>>(hs, Wq, Wk, Wv, Wo, relk, relv,
                                             hh, hl, wqh, wql, wkh, wkl,
                                             wvh, wvl, woh, wol, relkB, relvT);
    k_gemm_qkv<<<dim3(8, 32, 3), 256, 0, stream>>>(hh, hl, wqh, wkh, wvh,
                                                   bq, bk, bv, qbp, kbp, vtp);
    k_fused<<<dim3(64, 64), 256, 0, stream>>>(qbp, kbp, vtp, relkB, relvT, relv, c1, c2);
    // hh/hl are dead after k_gemm_qkv -> reuse as (c1+c2) hi/lo
    k_sum<<<dim3(2048), 256, 0, stream>>>(c1, c2, hh, hl);
    k_gemm_o<<<dim3(16, 32), 256, 0, stream>>>(hh, hl, woh, wol, bo, out);
}

// Round 8
// 374.905 us; speedup vs baseline: 1.2757x; 1.2757x over previous
//
#include <hip/hip_runtime.h>
#include <hip/hip_bf16.h>

// B=4, T=1024, E=1024, H=16, D=64, P=257.  Slot s = b*16+h (64 slots).
// Quirk: score slot m uses rel-K of slot pm=(m&15)*4+(m>>4); attn of slot m
// feeds w2 output of slot m2=(m&3)*16+(m>>2).
// R23: full revert of R22 (16-row tile: occ 61% but WRITE 33->125MB /
// FETCH 16->47MB amplification -> memory-bound at 221us).  k_fused back to
// R21 32-row structure, ONE change: sG double-buffered by kt-parity
// (sG[2][2][16][104], LDS 35.3->41.9KB, still 3/CU) -> trailing needG
// barrier deleted (reads of sG[b] at kt are 2 barriers ahead of the next
// write at kt+2; pre-barrier lgkmcnt drain makes this safe).
// R21: log2-domain softmax (Q pre-scaled 0.125*log2e), med3 jd clamp.
// R20: XCD swizzle.  R18/19: k_sum + qkv-clone k_gemm_o.  R16: qkv 128x128.

typedef __attribute__((ext_vector_type(8))) short short8;
typedef __attribute__((ext_vector_type(4))) float f32x4;

__device__ __forceinline__ float bf16f(unsigned int u) {
    union { unsigned int i; float f; } v; v.i = u << 16; return v.f;
}
__device__ __forceinline__ unsigned short f2b(float x) {
    __hip_bfloat16 h = __float2bfloat16(x);
    return *reinterpret_cast<unsigned short*>(&h);
}
__device__ __forceinline__ void gl_lds16(const unsigned short* g, unsigned short* l) {
    __builtin_amdgcn_global_load_lds(
        (const __attribute__((address_space(1))) void*)g,
        (__attribute__((address_space(3))) void*)l, 16, 0, 0);
}

// ---------------------------------------------------------------------------
// K0: prep.  z=0..4: split fp32 -> (hi,lo) bf16.  z=5: rel tables.
// lo halves skipped for Wq/Wk/Wv (z=1..3) - never read.
// ---------------------------------------------------------------------------
__global__ __launch_bounds__(256) void k_prep(
    const float* __restrict__ hs, const float* __restrict__ Wq,
    const float* __restrict__ Wk, const float* __restrict__ Wv,
    const float* __restrict__ Wo, const float* __restrict__ relk,
    const float* __restrict__ relv,
    unsigned short* __restrict__ hh, unsigned short* __restrict__ hl,
    unsigned short* __restrict__ wqh, unsigned short* __restrict__ wql,
    unsigned short* __restrict__ wkh, unsigned short* __restrict__ wkl,
    unsigned short* __restrict__ wvh, unsigned short* __restrict__ wvl,
    unsigned short* __restrict__ woh, unsigned short* __restrict__ wol,
    unsigned short* __restrict__ relkB, unsigned short* __restrict__ relvT)
{
    const int z = blockIdx.y;
    const int tid = threadIdx.x;
    if (z < 5) {
        const float* src = (z == 0) ? hs : (z == 1) ? Wq : (z == 2) ? Wk
                         : (z == 3) ? Wv : Wo;
        unsigned short* hi = (z == 0) ? hh : (z == 1) ? wqh : (z == 2) ? wkh
                           : (z == 3) ? wvh : woh;
        unsigned short* lo = (z == 0) ? hl : (z == 1) ? wql : (z == 2) ? wkl
                           : (z == 3) ? wvl : wol;
        const bool wlo = (z == 0) || (z == 4);
        const int n4 = (z == 0) ? 1048576 : 262144;
        const int stride = gridDim.x * 256;
        for (int i = blockIdx.x * 256 + tid; i < n4; i += stride) {
            float4 x = *(const float4*)(src + i*4);
            unsigned short h[4], l[4];
            float xs[4] = {x.x, x.y, x.z, x.w};
            #pragma unroll
            for (int j = 0; j < 4; ++j) {
                h[j] = f2b(xs[j]);
                l[j] = f2b(xs[j] - bf16f(h[j]));
            }
            *(ushort4*)(hi + i*4) = make_ushort4(h[0], h[1], h[2], h[3]);
            if (wlo)
                *(ushort4*)(lo + i*4) = make_ushort4(l[0], l[1], l[2], l[3]);
        }
    } else if (blockIdx.x == 0) {
        for (int i = tid; i < 272*64; i += 256) {
            int j = i >> 6;
            relkB[i] = (j < 257) ? f2b(relk[i]) : (unsigned short)0;
        }
        int d = tid >> 2, grp = tid & 3;
        for (int jj = 0; jj < 66; ++jj) {
            int j = grp*66 + jj;
            if (j < 264)
                relvT[d*264 + j] = (j < 257) ? f2b(relv[j*64 + d]) : (unsigned short)0;
        }
    }
}

// ---------------------------------------------------------------------------
// K1: QKV projection, 128x128 tile, double-buffered async staging, 2-MFMA
// split (AhBh + AlBh).  Grid (8, 32, 3) = 768 blocks = 3/CU, LDS 48 KB.
// R21: z==0 scale folds log2e (Q in log2 domain for k_fused's exp2).
// ---------------------------------------------------------------------------
__global__ __launch_bounds__(256, 3) void k_gemm_qkv(
    const unsigned short* __restrict__ hh, const unsigned short* __restrict__ hl,
    const unsigned short* __restrict__ wqh, const unsigned short* __restrict__ wkh,
    const unsigned short* __restrict__ wvh,
    const float* __restrict__ bq, const float* __restrict__ bk,
    const float* __restrict__ bv,
    unsigned short* __restrict__ qb, unsigned short* __restrict__ kb,
    unsigned short* __restrict__ vt)
{
    __shared__ __align__(16) unsigned short sAh[2][128][32];
    __shared__ __align__(16) unsigned short sAl[2][128][32];
    __shared__ __align__(16) unsigned short sBh[2][128][32];
    const int tid = threadIdx.x;
    // XCD-aware remap: d = hw linear id (768 = 8*96, bijective)
    const int d_ = blockIdx.x + (blockIdx.y << 3) + (blockIdx.z << 8);
    const int l_ = (d_ & 7) * 96 + (d_ >> 3);
    const int nbb = l_ / 24;
    const int r24 = l_ - nbb * 24;
    const int z   = r24 >> 3;
    const int ebb = r24 & 7;
    const int eb = ebb * 128, nb = nbb * 128;
    const unsigned short* Bh = (z == 0) ? wqh : (z == 1) ? wkh : wvh;
    const float* bias = (z == 0) ? bq : (z == 1) ? bk : bv;
    const float scale = (z == 0) ? 0.125f * 1.44269504f : 1.0f;
    const int w = tid >> 6, lane = tid & 63, lq = lane & 15, quad = lane >> 4;
    const int wr = w >> 1, wc = w & 1;

    const int prow = lane >> 2;
    const int pc8  = ((((lane & 3) - ((lane >> 3) & 3)) & 3)) * 8;
    const int arow = nb + w*16 + prow;
    const int brow = eb + w*16 + prow;

    f32x4 acc[4][4];
    #pragma unroll
    for (int i = 0; i < 4; ++i)
        #pragma unroll
        for (int j = 0; j < 4; ++j) acc[i][j] = (f32x4){0,0,0,0};

    const int pcol = ((quad + (lq >> 1)) & 3) * 8;   // swizzled frag column

    {
        gl_lds16(hh + (size_t)arow * 1024 + pc8,        &sAh[0][w*16][0]);
        gl_lds16(hh + (size_t)(arow + 64) * 1024 + pc8, &sAh[0][64 + w*16][0]);
        gl_lds16(hl + (size_t)arow * 1024 + pc8,        &sAl[0][w*16][0]);
        gl_lds16(hl + (size_t)(arow + 64) * 1024 + pc8, &sAl[0][64 + w*16][0]);
        gl_lds16(Bh + (size_t)brow * 1024 + pc8,        &sBh[0][w*16][0]);
        gl_lds16(Bh + (size_t)(brow + 64) * 1024 + pc8, &sBh[0][64 + w*16][0]);
    }

    for (int k0 = 0; k0 < 1024; k0 += 32) {
        const int cur = (k0 >> 5) & 1;
        __syncthreads();
        if (k0 < 992) {
            const int kn = k0 + 32, nxt = 1 - cur;
            gl_lds16(hh + (size_t)arow * 1024 + kn + pc8,        &sAh[nxt][w*16][0]);
            gl_lds16(hh + (size_t)(arow + 64) * 1024 + kn + pc8, &sAh[nxt][64 + w*16][0]);
            gl_lds16(hl + (size_t)arow * 1024 + kn + pc8,        &sAl[nxt][w*16][0]);
            gl_lds16(hl + (size_t)(arow + 64) * 1024 + kn + pc8, &sAl[nxt][64 + w*16][0]);
            gl_lds16(Bh + (size_t)brow * 1024 + kn + pc8,        &sBh[nxt][w*16][0]);
            gl_lds16(Bh + (size_t)(brow + 64) * 1024 + kn + pc8, &sBh[nxt][64 + w*16][0]);
        }

        short8 ah[4], al[4], bh4[4];
        #pragma unroll
        for (int t = 0; t < 4; ++t) {
            ah[t] = *(const short8*)&sAh[cur][wr*64 + t*16 + lq][pcol];
            al[t] = *(const short8*)&sAl[cur][wr*64 + t*16 + lq][pcol];
        }
        #pragma unroll
        for (int t = 0; t < 4; ++t)
            bh4[t] = *(const short8*)&sBh[cur][wc*64 + t*16 + lq][pcol];
        #pragma unroll
        for (int ti = 0; ti < 4; ++ti)
            #pragma unroll
            for (int tj = 0; tj < 4; ++tj) {
                acc[ti][tj] = __builtin_amdgcn_mfma_f32_16x16x32_bf16(ah[ti], bh4[tj], acc[ti][tj], 0, 0, 0);
                acc[ti][tj] = __builtin_amdgcn_mfma_f32_16x16x32_bf16(al[ti], bh4[tj], acc[ti][tj], 0, 0, 0);
            }
    }

    #pragma unroll
    for (int tj = 0; tj < 4; ++tj) {
        int e = eb + wc*64 + tj*16 + lq;
        float bb = bias[e];
        int h = e >> 6, d = e & 63;
        #pragma unroll
        for (int ti = 0; ti < 4; ++ti) {
            #pragma unroll
            for (int i = 0; i < 4; ++i) {
                int n = nb + wr*64 + ti*16 + quad*4 + i;
                int bidx = n >> 10, t = n & 1023;
                int s = bidx*16 + h;
                float val = (acc[ti][tj][i] + bb) * scale;
                if (z == 2)
                    vt[(((size_t)(s*64 + d)) << 10) + t] = f2b(val);
                else if (z == 0)
                    qb[(((size_t)(s*1024 + t)) << 6) + d] = f2b(val);
                else
                    kb[(((size_t)(s*1024 + t)) << 6) + d] = f2b(val);
            }
        }
    }
}

// ---------------------------------------------------------------------------
// K2: MFMA flash attention (R21 32-row structure).  R23: sG double-buffered
// by kt-parity -> trailing needG barrier removed.  R21: log2-domain softmax
// + med3 jd clamp.  R20: XCD swizzle.
// ---------------------------------------------------------------------------
__global__ __launch_bounds__(256) void k_fused(
    const unsigned short* __restrict__ qb, const unsigned short* __restrict__ kb,
    const unsigned short* __restrict__ vt, const unsigned short* __restrict__ relkB,
    const unsigned short* __restrict__ relvT, const float* __restrict__ relv,
    float* __restrict__ c1, float* __restrict__ c2)
{
    __shared__ __align__(16) unsigned short sP[2][2][16][72];
    __shared__ __align__(16) unsigned short sG[2][2][16][104];
    __shared__ unsigned short sR[32][273];
    __shared__ float sRed[4][3][32];

    const int tid = threadIdx.x;
    // XCD-aware remap: 2048 blocks = 8 * 256, bijective
    const int d_ = blockIdx.x + (blockIdx.y << 5);
    const int l_ = (d_ & 7) * 256 + (d_ >> 3);
    const int m  = l_ >> 5;
    const int q0 = (l_ & 31) * 32;
    const int pm = (m & 15) * 4 + (m >> 4);
    const int m2 = (m & 3) * 16 + (m >> 2);
    const int w    = tid >> 6;
    const int lane = tid & 63;
    const int lq   = lane & 15;
    const int quad = lane >> 4;

    #pragma unroll
    for (int sub = 0; sub < 2; ++sub) {
        const unsigned short* qpm = qb + (((size_t)(pm*1024 + q0 + sub*16 + lq)) << 6);
        short8 a0 = *(const short8*)(qpm + quad*8);
        short8 a1 = *(const short8*)(qpm + 32 + quad*8);
        for (int jt = w; jt < 17; jt += 4) {
            const unsigned short* rkb = relkB + (size_t)(jt*16 + lq) * 64;
            short8 b0 = *(const short8*)(rkb + quad*8);
            short8 b1 = *(const short8*)(rkb + 32 + quad*8);
            f32x4 cr = {0,0,0,0};
            cr = __builtin_amdgcn_mfma_f32_16x16x32_bf16(a0, b0, cr, 0, 0, 0);
            cr = __builtin_amdgcn_mfma_f32_16x16x32_bf16(a1, b1, cr, 0, 0, 0);
            #pragma unroll
            for (int i = 0; i < 4; ++i)
                sR[sub*16 + quad*4 + i][jt*16 + lq] = f2b(cr[i]);
        }
    }
    __syncthreads();

    short8 aq0[2], aq1[2];
    #pragma unroll
    for (int sub = 0; sub < 2; ++sub) {
        const unsigned short* qm = qb + (((size_t)(m*1024 + q0 + sub*16 + lq)) << 6);
        aq0[sub] = *(const short8*)(qm + quad*8);
        aq1[sub] = *(const short8*)(qm + 32 + quad*8);
    }
    const float relE0 = relv[w*16 + lq];
    const float relE1 = relv[256*64 + w*16 + lq];

    float lsum[2][4], slow[2][4], shigh[2][4];
    f32x4 c1a[2], c2a[2];
    #pragma unroll
    for (int sub = 0; sub < 2; ++sub) {
        c1a[sub] = (f32x4){0,0,0,0};
        c2a[sub] = (f32x4){0,0,0,0};
        #pragma unroll
        for (int i = 0; i < 4; ++i) {
            lsum[sub][i] = 0.0f; slow[sub][i] = 0.0f; shigh[sub][i] = 0.0f;
        }
    }

    const unsigned short* kbase = kb + (((size_t)(m*1024 + w*16 + lq)) << 6);
    const unsigned short* vbase = vt + (((size_t)(m*64 + w*16 + lq)) << 10);
    short8 ck0 = *(const short8*)(kbase + quad*8);
    short8 ck1 = *(const short8*)(kbase + 32 + quad*8);
    short8 cv0 = *(const short8*)(vbase + quad*8);
    short8 cv1 = *(const short8*)(vbase + 32 + quad*8);

    // jd = clamp(jbase + row - 64*kt, 0, 256), row = sub*16+quad*4+i
    const int jbase = q0 + 128 - (w*16 + lq);

    #pragma unroll 1
    for (int kt = 0; kt < 16; ++kt) {
        const int k0 = kt * 64;
        const int dmin = q0 - k0 - 63;
        const int dmax = q0 + 31 - k0;
        const bool needG = (dmax >= -127) && (dmin <= 127);
        const int buf = kt & 1;
        const int jb = jbase - k0;

        short8 nk0 = ck0, nk1 = ck1, nv0 = cv0, nv1 = cv1;
        if (kt < 15) {
            const size_t ko = (size_t)(k0 + 64);
            nk0 = *(const short8*)(kbase + (ko << 6) + quad*8);
            nk1 = *(const short8*)(kbase + (ko << 6) + 32 + quad*8);
            nv0 = *(const short8*)(vbase + ko + quad*8);
            nv1 = *(const short8*)(vbase + ko + 32 + quad*8);
        }

        f32x4 s4[2];
        #pragma unroll
        for (int sub = 0; sub < 2; ++sub) {
            s4[sub] = (f32x4){0,0,0,0};
            s4[sub] = __builtin_amdgcn_mfma_f32_16x16x32_bf16(aq0[sub], ck0, s4[sub], 0, 0, 0);
            s4[sub] = __builtin_amdgcn_mfma_f32_16x16x32_bf16(aq1[sub], ck1, s4[sub], 0, 0, 0);
        }

        float e[2][4];
        #pragma unroll
        for (int sub = 0; sub < 2; ++sub) {
            #pragma unroll
            for (int i = 0; i < 4; ++i) {
                int row = sub*16 + quad*4 + i;
                int jd = jb + row;
                jd = jd < 0 ? 0 : jd;
                jd = jd > 256 ? 256 : jd;
                float ev = exp2f(s4[sub][i] + bf16f(sR[row][jd]));
                e[sub][i] = ev;
                lsum[sub][i] += ev;
                if (jd == 0)        slow[sub][i]  += ev;
                else if (jd == 256) shigh[sub][i] += ev;
                sP[buf][sub][quad*4 + i][w*16 + lq] = f2b(ev);
            }
        }
        if (needG) {
            unsigned int* gz = (unsigned int*)&sG[buf][0][0][0];
            #pragma unroll
            for (int i = 0; i < 7; ++i) {
                int idx = tid + i * 256;
                if (idx < 1664) gz[idx] = 0u;
            }
        }
        __syncthreads();

        if (needG) {
            #pragma unroll
            for (int sub = 0; sub < 2; ++sub) {
                int jminb = q0 + sub*16 - k0 - 63;
                jminb = (jminb < -127 ? -127 : jminb) + 128;
                int jlo8 = jminb & ~7;
                if (jlo8 > 160) jlo8 = 160;
                #pragma unroll
                for (int i = 0; i < 4; ++i) {
                    int jd = jb + sub*16 + quad*4 + i;   // interior: equals clamped jd
                    if (jd > 0 && jd < 256)
                        sG[buf][sub][quad*4 + i][jd - jlo8] = f2b(e[sub][i]);
                }
            }
        }

        #pragma unroll
        for (int sub = 0; sub < 2; ++sub) {
            short8 ap0 = *(const short8*)&sP[buf][sub][lq][quad*8];
            short8 ap1 = *(const short8*)&sP[buf][sub][lq][32 + quad*8];
            c1a[sub] = __builtin_amdgcn_mfma_f32_16x16x32_bf16(ap0, cv0, c1a[sub], 0, 0, 0);
            c1a[sub] = __builtin_amdgcn_mfma_f32_16x16x32_bf16(ap1, cv1, c1a[sub], 0, 0, 0);
        }

        if (needG) {
            __syncthreads();
            #pragma unroll
            for (int sub = 0; sub < 2; ++sub) {
                int jminb = q0 + sub*16 - k0 - 63;
                jminb = (jminb < -127 ? -127 : jminb) + 128;
                int jlo8 = jminb & ~7;
                if (jlo8 > 160) jlo8 = 160;
                short8 ag0 = *(const short8*)&sG[buf][sub][lq][quad*8];
                short8 ag1 = *(const short8*)&sG[buf][sub][lq][32 + quad*8];
                short8 ag2 = *(const short8*)&sG[buf][sub][lq][64 + quad*8];
                const unsigned short* rrow = relvT + (size_t)(w*16 + lq) * 264 + jlo8;
                short8 br0 = *(const short8*)(rrow + quad*8);
                short8 br1 = *(const short8*)(rrow + 32 + quad*8);
                short8 br2 = *(const short8*)(rrow + 64 + quad*8);
                c2a[sub] = __builtin_amdgcn_mfma_f32_16x16x32_bf16(ag0, br0, c2a[sub], 0, 0, 0);
                c2a[sub] = __builtin_amdgcn_mfma_f32_16x16x32_bf16(ag1, br1, c2a[sub], 0, 0, 0);
                c2a[sub] = __builtin_amdgcn_mfma_f32_16x16x32_bf16(ag2, br2, c2a[sub], 0, 0, 0);
            }
            // trailing barrier removed: next write to sG[buf] is at kt+2,
            // two barriers away (A_{kt+1}, B_{kt+1}) -> race-free.
        }

        ck0 = nk0; ck1 = nk1; cv0 = nv0; cv1 = nv1;
    }

    #pragma unroll
    for (int off = 1; off < 16; off <<= 1) {
        #pragma unroll
        for (int sub = 0; sub < 2; ++sub)
            #pragma unroll
            for (int i = 0; i < 4; ++i) {
                lsum[sub][i]  += __shfl_xor(lsum[sub][i],  off, 64);
                slow[sub][i]  += __shfl_xor(slow[sub][i],  off, 64);
                shigh[sub][i] += __shfl_xor(shigh[sub][i], off, 64);
            }
    }
    if (lq == 0) {
        #pragma unroll
        for (int sub = 0; sub < 2; ++sub)
            #pragma unroll
            for (int i = 0; i < 4; ++i) {
                int row = sub*16 + quad*4 + i;
                sRed[w][0][row] = lsum[sub][i];
                sRed[w][1][row] = slow[sub][i];
                sRed[w][2][row] = shigh[sub][i];
            }
    }
    __syncthreads();

    const int b1 = m >> 4,  h1 = m & 15;
    const int b2 = m2 >> 4, h2 = m2 & 15;
    #pragma unroll
    for (int sub = 0; sub < 2; ++sub) {
        #pragma unroll
        for (int i = 0; i < 4; ++i) {
            int row = sub*16 + quad*4 + i;
            float lt = sRed[0][0][row] + sRed[1][0][row] + sRed[2][0][row] + sRed[3][0][row];
            float sl = sRed[0][1][row] + sRed[1][1][row] + sRed[2][1][row] + sRed[3][1][row];
            float sh = sRed[0][2][row] + sRed[1][2][row] + sRed[2][2][row] + sRed[3][2][row];
            float c2v = c2a[sub][i] + sl * relE0 + sh * relE1;
            float inv = 1.0f / lt;
            int col = w*16 + lq;
            c1[(size_t)(b1*1024 + q0 + row) * 1024 + h1*64 + col] = c1a[sub][i] * inv;
            c2[(size_t)(b2*1024 + q0 + row) * 1024 + h2*64 + col] = c2v * inv;
        }
    }
}

// ---------------------------------------------------------------------------
// K2b: A = c1+c2 -> bf16 (hi,lo) split, written into the dead hh/hl buffers.
// ---------------------------------------------------------------------------
__global__ __launch_bounds__(256) void k_sum(
    const float* __restrict__ c1, const float* __restrict__ c2,
    unsigned short* __restrict__ ah, unsigned short* __restrict__ al)
{
    const int stride = gridDim.x * 256;
    for (int i = blockIdx.x * 256 + threadIdx.x; i < 1048576; i += stride) {
        float4 a = *(const float4*)(c1 + i*4);
        float4 b = *(const float4*)(c2 + i*4);
        float s[4] = {a.x+b.x, a.y+b.y, a.z+b.z, a.w+b.w};
        unsigned short h[4], l[4];
        #pragma unroll
        for (int j = 0; j < 4; ++j) {
            h[j] = f2b(s[j]);
            l[j] = f2b(s[j] - bf16f(h[j]));
        }
        *(ushort4*)(ah + i*4) = make_ushort4(h[0], h[1], h[2], h[3]);
        *(ushort4*)(al + i*4) = make_ushort4(l[0], l[1], l[2], l[3]);
    }
}

// ---------------------------------------------------------------------------
// K3: out = A @ Wo^T + bo with A = pre-split (c1+c2) hi/lo.  qkv-clone:
// 128x64 tile, cross-iteration async dbuf staging, 3-MFMA (AhBh+AlBh+AhBl).
// Grid (16,32) = 512 blocks, LDS 48 KB.  R20: XCD swizzle, same-nb (16
// eb-blocks, shared A-panel) contiguous per XCD.
// ---------------------------------------------------------------------------
__global__ __launch_bounds__(256, 3) void k_gemm_o(
    const unsigned short* __restrict__ ah_, const unsigned short* __restrict__ al_,
    const unsigned short* __restrict__ woh, const unsigned short* __restrict__ wol,
    const float* __restrict__ bo, float* __restrict__ outp)
{
    __shared__ __align__(16) unsigned short sAh[2][128][32];
    __shared__ __align__(16) unsigned short sAl[2][128][32];
    __shared__ __align__(16) unsigned short sBh[2][64][32];
    __shared__ __align__(16) unsigned short sBl[2][64][32];
    const int tid = threadIdx.x;
    // XCD-aware remap: 512 blocks = 8 * 64, bijective
    const int d_ = blockIdx.x + (blockIdx.y << 4);
    const int l_ = (d_ & 7) * 64 + (d_ >> 3);
    const int eb = (l_ & 15) * 64, nb = (l_ >> 4) * 128;
    const int w = tid >> 6, lane = tid & 63, lq = lane & 15, quad = lane >> 4;
    const int wr = w >> 1, wc = w & 1;

    const int prow = lane >> 2;
    const int pc8  = ((((lane & 3) - ((lane >> 3) & 3)) & 3)) * 8;
    const int arow = nb + w*16 + prow;
    const int brow = eb + w*16 + prow;

    f32x4 acc[4][2];
    #pragma unroll
    for (int i = 0; i < 4; ++i)
        #pragma unroll
        for (int j = 0; j < 2; ++j) acc[i][j] = (f32x4){0,0,0,0};

    const int pcol = ((quad + (lq >> 1)) & 3) * 8;

    // prologue: stage tile 0 into buf 0
    {
        gl_lds16(ah_ + (size_t)arow * 1024 + pc8,        &sAh[0][w*16][0]);
        gl_lds16(ah_ + (size_t)(arow + 64) * 1024 + pc8, &sAh[0][64 + w*16][0]);
        gl_lds16(al_ + (size_t)arow * 1024 + pc8,        &sAl[0][w*16][0]);
        gl_lds16(al_ + (size_t)(arow + 64) * 1024 + pc8, &sAl[0][64 + w*16][0]);
        gl_lds16(woh + (size_t)brow * 1024 + pc8,        &sBh[0][w*16][0]);
        gl_lds16(wol + (size_t)brow * 1024 + pc8,        &sBl[0][w*16][0]);
    }

    for (int k0 = 0; k0 < 1024; k0 += 32) {
        const int cur = (k0 >> 5) & 1;
        __syncthreads();
        if (k0 < 992) {
            const int kn = k0 + 32, nxt = 1 - cur;
            gl_lds16(ah_ + (size_t)arow * 1024 + kn + pc8,        &sAh[nxt][w*16][0]);
            gl_lds16(ah_ + (size_t)(arow + 64) * 1024 + kn + pc8, &sAh[nxt][64 + w*16][0]);
            gl_lds16(al_ + (size_t)arow * 1024 + kn + pc8,        &sAl[nxt][w*16][0]);
            gl_lds16(al_ + (size_t)(arow + 64) * 1024 + kn + pc8, &sAl[nxt][64 + w*16][0]);
            gl_lds16(woh + (size_t)brow * 1024 + kn + pc8,        &sBh[nxt][w*16][0]);
            gl_lds16(wol + (size_t)brow * 1024 + kn + pc8,        &sBl[nxt][w*16][0]);
        }

        short8 ah[4], al[4], bhf[2], blf[2];
        #pragma unroll
        for (int t = 0; t < 4; ++t) {
            ah[t] = *(const short8*)&sAh[cur][wr*64 + t*16 + lq][pcol];
            al[t] = *(const short8*)&sAl[cur][wr*64 + t*16 + lq][pcol];
        }
        #pragma unroll
        for (int t = 0; t < 2; ++t) {
            bhf[t] = *(const short8*)&sBh[cur][wc*32 + t*16 + lq][pcol];
            blf[t] = *(const short8*)&sBl[cur][wc*32 + t*16 + lq][pcol];
        }
        #pragma unroll
        for (int ti = 0; ti < 4; ++ti)
            #pragma unroll
            for (int tj = 0; tj < 2; ++tj) {
                acc[ti][tj] = __builtin_amdgcn_mfma_f32_16x16x32_bf16(ah[ti], bhf[tj], acc[ti][tj], 0, 0, 0);
                acc[ti][tj] = __builtin_amdgcn_mfma_f32_16x16x32_bf16(al[ti], bhf[tj], acc[ti][tj], 0, 0, 0);
                acc[ti][tj] = __builtin_amdgcn_mfma_f32_16x16x32_bf16(ah[ti], blf[tj], acc[ti][tj], 0, 0, 0);
            }
    }

    #pragma unroll
    for (int tj = 0; tj < 2; ++tj) {
        int e = eb + wc*32 + tj*16 + lq;
        float bb = bo[e];
        #pragma unroll
        for (int ti = 0; ti < 4; ++ti) {
            #pragma unroll
            for (int i = 0; i < 4; ++i) {
                int n = nb + wr*64 + ti*16 + quad*4 + i;
                outp[(size_t)n * 1024 + e] = acc[ti][tj][i] + bb;
            }
        }
    }
}

// ---------------------------------------------------------------------------
extern "C" void kernel_launch(void* const* d_in, const int* in_sizes, int n_in,
                              void* d_out, int out_size, void* d_ws, size_t ws_size,
                              hipStream_t stream) {
    const float* hs   = (const float*)d_in[0];
    const float* Wq   = (const float*)d_in[1];
    const float* bq   = (const float*)d_in[2];
    const float* Wk   = (const float*)d_in[3];
    const float* bk   = (const float*)d_in[4];
    const float* Wv   = (const float*)d_in[5];
    const float* bv   = (const float*)d_in[6];
    const float* Wo   = (const float*)d_in[7];
    const float* bo   = (const float*)d_in[8];
    const float* relk = (const float*)d_in[9];
    const float* relv = (const float*)d_in[10];
    float* out = (float*)d_out;

    unsigned short* wsu = (unsigned short*)d_ws;
    unsigned short* qbp   = wsu;
    unsigned short* kbp   = wsu + 4194304;
    unsigned short* vtp   = wsu + 8388608;
    unsigned short* relkB = wsu + 12582912;
    unsigned short* relvT = wsu + 12600320;
    float* c1 = (float*)(wsu + 12617360);
    float* c2 = c1 + 4194304;
    unsigned short* hh  = wsu + 29394576;
    unsigned short* hl  = hh + 4194304;
    unsigned short* wqh = hl + 4194304;
    unsigned short* wql = wqh + 1048576;
    unsigned short* wkh = wql + 1048576;
    unsigned short* wkl = wkh + 1048576;
    unsigned short* wvh = wkl + 1048576;
    unsigned short* wvl = wvh + 1048576;
    unsigned short* woh = wvl + 1048576;
    unsigned short* wol = woh + 1048576;

    k_prep<<<dim3(512, 6), 256, 0, stream>>>(hs, Wq, Wk, Wv, Wo, relk, relv,
                                             hh, hl, wqh, wql, wkh, wkl,
                                             wvh, wvl, woh, wol, relkB, relvT);
    k_gemm_qkv<<<dim3(8, 32, 3), 256, 0, stream>>>(hh, hl, wqh, wkh, wvh,
                                                   bq, bk, bv, qbp, kbp, vtp);
    k_fused<<<dim3(32, 64), 256, 0, stream>>>(qbp, kbp, vtp, relkB, relvT, relv, c1, c2);
    // hh/hl are dead after k_gemm_qkv -> reuse as (c1+c2) hi/lo
    k_sum<<<dim3(2048), 256, 0, stream>>>(c1, c2, hh, hl);
    k_gemm_o<<<dim3(16, 32), 256, 0, stream>>>(hh, hl, woh, wol, bo, out);
}

// Round 9
// 367.996 us; speedup vs baseline: 1.2997x; 1.0188x over previous
//
#include <hip/hip_runtime.h>
#include <hip/hip_bf16.h>

// B=4, T=1024, E=1024, H=16, D=64, P=257.  Slot s = b*16+h (64 slots).
// Quirk: score slot m uses rel-K of slot pm=(m&15)*4+(m>>4); attn of slot m
// feeds w2 output of slot m2=(m&3)*16+(m>>2).
// R24: k_fused reverted verbatim to R21 (R23 sG-dbuf cost a resident block:
// LDS 42K -> 3 blocks/CU, occ 20.9%, 132us).  k_fused occupancy is pinned at
// 4 blocks/CU by LDS=35.3K AND VGPR=84 jointly -> left as local optimum.
// k_gemm_o re-tiled 128x64 -> 64x64 (1024 blocks = 4/CU residency vs 2/CU,
// LDS 32KB; R16 mechanism: residency-starved GEMM).  Output bit-identical.
// R21: log2-domain softmax (Q pre-scaled 0.125*log2e), med3 jd clamp.
// R20: XCD swizzle.  R18/19: k_sum + qkv-clone k_gemm_o.  R16: qkv 128x128.

typedef __attribute__((ext_vector_type(8))) short short8;
typedef __attribute__((ext_vector_type(4))) float f32x4;

__device__ __forceinline__ float bf16f(unsigned int u) {
    union { unsigned int i; float f; } v; v.i = u << 16; return v.f;
}
__device__ __forceinline__ unsigned short f2b(float x) {
    __hip_bfloat16 h = __float2bfloat16(x);
    return *reinterpret_cast<unsigned short*>(&h);
}
__device__ __forceinline__ void gl_lds16(const unsigned short* g, unsigned short* l) {
    __builtin_amdgcn_global_load_lds(
        (const __attribute__((address_space(1))) void*)g,
        (__attribute__((address_space(3))) void*)l, 16, 0, 0);
}

// ---------------------------------------------------------------------------
// K0: prep.  z=0..4: split fp32 -> (hi,lo) bf16.  z=5: rel tables.
// lo halves skipped for Wq/Wk/Wv (z=1..3) - never read.
// ---------------------------------------------------------------------------
__global__ __launch_bounds__(256) void k_prep(
    const float* __restrict__ hs, const float* __restrict__ Wq,
    const float* __restrict__ Wk, const float* __restrict__ Wv,
    const float* __restrict__ Wo, const float* __restrict__ relk,
    const float* __restrict__ relv,
    unsigned short* __restrict__ hh, unsigned short* __restrict__ hl,
    unsigned short* __restrict__ wqh, unsigned short* __restrict__ wql,
    unsigned short* __restrict__ wkh, unsigned short* __restrict__ wkl,
    unsigned short* __restrict__ wvh, unsigned short* __restrict__ wvl,
    unsigned short* __restrict__ woh, unsigned short* __restrict__ wol,
    unsigned short* __restrict__ relkB, unsigned short* __restrict__ relvT)
{
    const int z = blockIdx.y;
    const int tid = threadIdx.x;
    if (z < 5) {
        const float* src = (z == 0) ? hs : (z == 1) ? Wq : (z == 2) ? Wk
                         : (z == 3) ? Wv : Wo;
        unsigned short* hi = (z == 0) ? hh : (z == 1) ? wqh : (z == 2) ? wkh
                           : (z == 3) ? wvh : woh;
        unsigned short* lo = (z == 0) ? hl : (z == 1) ? wql : (z == 2) ? wkl
                           : (z == 3) ? wvl : wol;
        const bool wlo = (z == 0) || (z == 4);
        const int n4 = (z == 0) ? 1048576 : 262144;
        const int stride = gridDim.x * 256;
        for (int i = blockIdx.x * 256 + tid; i < n4; i += stride) {
            float4 x = *(const float4*)(src + i*4);
            unsigned short h[4], l[4];
            float xs[4] = {x.x, x.y, x.z, x.w};
            #pragma unroll
            for (int j = 0; j < 4; ++j) {
                h[j] = f2b(xs[j]);
                l[j] = f2b(xs[j] - bf16f(h[j]));
            }
            *(ushort4*)(hi + i*4) = make_ushort4(h[0], h[1], h[2], h[3]);
            if (wlo)
                *(ushort4*)(lo + i*4) = make_ushort4(l[0], l[1], l[2], l[3]);
        }
    } else if (blockIdx.x == 0) {
        for (int i = tid; i < 272*64; i += 256) {
            int j = i >> 6;
            relkB[i] = (j < 257) ? f2b(relk[i]) : (unsigned short)0;
        }
        int d = tid >> 2, grp = tid & 3;
        for (int jj = 0; jj < 66; ++jj) {
            int j = grp*66 + jj;
            if (j < 264)
                relvT[d*264 + j] = (j < 257) ? f2b(relv[j*64 + d]) : (unsigned short)0;
        }
    }
}

// ---------------------------------------------------------------------------
// K1: QKV projection, 128x128 tile, double-buffered async staging, 2-MFMA
// split (AhBh + AlBh).  Grid (8, 32, 3) = 768 blocks = 3/CU, LDS 48 KB.
// R21: z==0 scale folds log2e (Q in log2 domain for k_fused's exp2).
// ---------------------------------------------------------------------------
__global__ __launch_bounds__(256, 3) void k_gemm_qkv(
    const unsigned short* __restrict__ hh, const unsigned short* __restrict__ hl,
    const unsigned short* __restrict__ wqh, const unsigned short* __restrict__ wkh,
    const unsigned short* __restrict__ wvh,
    const float* __restrict__ bq, const float* __restrict__ bk,
    const float* __restrict__ bv,
    unsigned short* __restrict__ qb, unsigned short* __restrict__ kb,
    unsigned short* __restrict__ vt)
{
    __shared__ __align__(16) unsigned short sAh[2][128][32];
    __shared__ __align__(16) unsigned short sAl[2][128][32];
    __shared__ __align__(16) unsigned short sBh[2][128][32];
    const int tid = threadIdx.x;
    // XCD-aware remap: d = hw linear id (768 = 8*96, bijective)
    const int d_ = blockIdx.x + (blockIdx.y << 3) + (blockIdx.z << 8);
    const int l_ = (d_ & 7) * 96 + (d_ >> 3);
    const int nbb = l_ / 24;
    const int r24 = l_ - nbb * 24;
    const int z   = r24 >> 3;
    const int ebb = r24 & 7;
    const int eb = ebb * 128, nb = nbb * 128;
    const unsigned short* Bh = (z == 0) ? wqh : (z == 1) ? wkh : wvh;
    const float* bias = (z == 0) ? bq : (z == 1) ? bk : bv;
    const float scale = (z == 0) ? 0.125f * 1.44269504f : 1.0f;
    const int w = tid >> 6, lane = tid & 63, lq = lane & 15, quad = lane >> 4;
    const int wr = w >> 1, wc = w & 1;

    const int prow = lane >> 2;
    const int pc8  = ((((lane & 3) - ((lane >> 3) & 3)) & 3)) * 8;
    const int arow = nb + w*16 + prow;
    const int brow = eb + w*16 + prow;

    f32x4 acc[4][4];
    #pragma unroll
    for (int i = 0; i < 4; ++i)
        #pragma unroll
        for (int j = 0; j < 4; ++j) acc[i][j] = (f32x4){0,0,0,0};

    const int pcol = ((quad + (lq >> 1)) & 3) * 8;   // swizzled frag column

    {
        gl_lds16(hh + (size_t)arow * 1024 + pc8,        &sAh[0][w*16][0]);
        gl_lds16(hh + (size_t)(arow + 64) * 1024 + pc8, &sAh[0][64 + w*16][0]);
        gl_lds16(hl + (size_t)arow * 1024 + pc8,        &sAl[0][w*16][0]);
        gl_lds16(hl + (size_t)(arow + 64) * 1024 + pc8, &sAl[0][64 + w*16][0]);
        gl_lds16(Bh + (size_t)brow * 1024 + pc8,        &sBh[0][w*16][0]);
        gl_lds16(Bh + (size_t)(brow + 64) * 1024 + pc8, &sBh[0][64 + w*16][0]);
    }

    for (int k0 = 0; k0 < 1024; k0 += 32) {
        const int cur = (k0 >> 5) & 1;
        __syncthreads();
        if (k0 < 992) {
            const int kn = k0 + 32, nxt = 1 - cur;
            gl_lds16(hh + (size_t)arow * 1024 + kn + pc8,        &sAh[nxt][w*16][0]);
            gl_lds16(hh + (size_t)(arow + 64) * 1024 + kn + pc8, &sAh[nxt][64 + w*16][0]);
            gl_lds16(hl + (size_t)arow * 1024 + kn + pc8,        &sAl[nxt][w*16][0]);
            gl_lds16(hl + (size_t)(arow + 64) * 1024 + kn + pc8, &sAl[nxt][64 + w*16][0]);
            gl_lds16(Bh + (size_t)brow * 1024 + kn + pc8,        &sBh[nxt][w*16][0]);
            gl_lds16(Bh + (size_t)(brow + 64) * 1024 + kn + pc8, &sBh[nxt][64 + w*16][0]);
        }

        short8 ah[4], al[4], bh4[4];
        #pragma unroll
        for (int t = 0; t < 4; ++t) {
            ah[t] = *(const short8*)&sAh[cur][wr*64 + t*16 + lq][pcol];
            al[t] = *(const short8*)&sAl[cur][wr*64 + t*16 + lq][pcol];
        }
        #pragma unroll
        for (int t = 0; t < 4; ++t)
            bh4[t] = *(const short8*)&sBh[cur][wc*64 + t*16 + lq][pcol];
        #pragma unroll
        for (int ti = 0; ti < 4; ++ti)
            #pragma unroll
            for (int tj = 0; tj < 4; ++tj) {
                acc[ti][tj] = __builtin_amdgcn_mfma_f32_16x16x32_bf16(ah[ti], bh4[tj], acc[ti][tj], 0, 0, 0);
                acc[ti][tj] = __builtin_amdgcn_mfma_f32_16x16x32_bf16(al[ti], bh4[tj], acc[ti][tj], 0, 0, 0);
            }
    }

    #pragma unroll
    for (int tj = 0; tj < 4; ++tj) {
        int e = eb + wc*64 + tj*16 + lq;
        float bb = bias[e];
        int h = e >> 6, d = e & 63;
        #pragma unroll
        for (int ti = 0; ti < 4; ++ti) {
            #pragma unroll
            for (int i = 0; i < 4; ++i) {
                int n = nb + wr*64 + ti*16 + quad*4 + i;
                int bidx = n >> 10, t = n & 1023;
                int s = bidx*16 + h;
                float val = (acc[ti][tj][i] + bb) * scale;
                if (z == 2)
                    vt[(((size_t)(s*64 + d)) << 10) + t] = f2b(val);
                else if (z == 0)
                    qb[(((size_t)(s*1024 + t)) << 6) + d] = f2b(val);
                else
                    kb[(((size_t)(s*1024 + t)) << 6) + d] = f2b(val);
            }
        }
    }
}

// ---------------------------------------------------------------------------
// K2: MFMA flash attention (verbatim R21).  log2-domain softmax + med3 jd
// clamp; XCD swizzle.  LDS 35.3 KB / VGPR 84 -> 4 blocks/CU (local optimum).
// ---------------------------------------------------------------------------
__global__ __launch_bounds__(256) void k_fused(
    const unsigned short* __restrict__ qb, const unsigned short* __restrict__ kb,
    const unsigned short* __restrict__ vt, const unsigned short* __restrict__ relkB,
    const unsigned short* __restrict__ relvT, const float* __restrict__ relv,
    float* __restrict__ c1, float* __restrict__ c2)
{
    __shared__ __align__(16) unsigned short sP[2][2][16][72];
    __shared__ __align__(16) unsigned short sG[2][16][104];
    __shared__ unsigned short sR[32][273];
    __shared__ float sRed[4][3][32];

    const int tid = threadIdx.x;
    // XCD-aware remap: 2048 blocks = 8 * 256, bijective
    const int d_ = blockIdx.x + (blockIdx.y << 5);
    const int l_ = (d_ & 7) * 256 + (d_ >> 3);
    const int m  = l_ >> 5;
    const int q0 = (l_ & 31) * 32;
    const int pm = (m & 15) * 4 + (m >> 4);
    const int m2 = (m & 3) * 16 + (m >> 2);
    const int w    = tid >> 6;
    const int lane = tid & 63;
    const int lq   = lane & 15;
    const int quad = lane >> 4;

    #pragma unroll
    for (int sub = 0; sub < 2; ++sub) {
        const unsigned short* qpm = qb + (((size_t)(pm*1024 + q0 + sub*16 + lq)) << 6);
        short8 a0 = *(const short8*)(qpm + quad*8);
        short8 a1 = *(const short8*)(qpm + 32 + quad*8);
        for (int jt = w; jt < 17; jt += 4) {
            const unsigned short* rkb = relkB + (size_t)(jt*16 + lq) * 64;
            short8 b0 = *(const short8*)(rkb + quad*8);
            short8 b1 = *(const short8*)(rkb + 32 + quad*8);
            f32x4 cr = {0,0,0,0};
            cr = __builtin_amdgcn_mfma_f32_16x16x32_bf16(a0, b0, cr, 0, 0, 0);
            cr = __builtin_amdgcn_mfma_f32_16x16x32_bf16(a1, b1, cr, 0, 0, 0);
            #pragma unroll
            for (int i = 0; i < 4; ++i)
                sR[sub*16 + quad*4 + i][jt*16 + lq] = f2b(cr[i]);
        }
    }
    __syncthreads();

    short8 aq0[2], aq1[2];
    #pragma unroll
    for (int sub = 0; sub < 2; ++sub) {
        const unsigned short* qm = qb + (((size_t)(m*1024 + q0 + sub*16 + lq)) << 6);
        aq0[sub] = *(const short8*)(qm + quad*8);
        aq1[sub] = *(const short8*)(qm + 32 + quad*8);
    }
    const float relE0 = relv[w*16 + lq];
    const float relE1 = relv[256*64 + w*16 + lq];

    float lsum[2][4], slow[2][4], shigh[2][4];
    f32x4 c1a[2], c2a[2];
    #pragma unroll
    for (int sub = 0; sub < 2; ++sub) {
        c1a[sub] = (f32x4){0,0,0,0};
        c2a[sub] = (f32x4){0,0,0,0};
        #pragma unroll
        for (int i = 0; i < 4; ++i) {
            lsum[sub][i] = 0.0f; slow[sub][i] = 0.0f; shigh[sub][i] = 0.0f;
        }
    }

    const unsigned short* kbase = kb + (((size_t)(m*1024 + w*16 + lq)) << 6);
    const unsigned short* vbase = vt + (((size_t)(m*64 + w*16 + lq)) << 10);
    short8 ck0 = *(const short8*)(kbase + quad*8);
    short8 ck1 = *(const short8*)(kbase + 32 + quad*8);
    short8 cv0 = *(const short8*)(vbase + quad*8);
    short8 cv1 = *(const short8*)(vbase + 32 + quad*8);

    // jd = clamp(jbase + row - 64*kt, 0, 256), row = sub*16+quad*4+i
    const int jbase = q0 + 128 - (w*16 + lq);

    #pragma unroll 1
    for (int kt = 0; kt < 16; ++kt) {
        const int k0 = kt * 64;
        const int dmin = q0 - k0 - 63;
        const int dmax = q0 + 31 - k0;
        const bool needG = (dmax >= -127) && (dmin <= 127);
        const int buf = kt & 1;
        const int jb = jbase - k0;

        short8 nk0 = ck0, nk1 = ck1, nv0 = cv0, nv1 = cv1;
        if (kt < 15) {
            const size_t ko = (size_t)(k0 + 64);
            nk0 = *(const short8*)(kbase + (ko << 6) + quad*8);
            nk1 = *(const short8*)(kbase + (ko << 6) + 32 + quad*8);
            nv0 = *(const short8*)(vbase + ko + quad*8);
            nv1 = *(const short8*)(vbase + ko + 32 + quad*8);
        }

        f32x4 s4[2];
        #pragma unroll
        for (int sub = 0; sub < 2; ++sub) {
            s4[sub] = (f32x4){0,0,0,0};
            s4[sub] = __builtin_amdgcn_mfma_f32_16x16x32_bf16(aq0[sub], ck0, s4[sub], 0, 0, 0);
            s4[sub] = __builtin_amdgcn_mfma_f32_16x16x32_bf16(aq1[sub], ck1, s4[sub], 0, 0, 0);
        }

        float e[2][4];
        #pragma unroll
        for (int sub = 0; sub < 2; ++sub) {
            #pragma unroll
            for (int i = 0; i < 4; ++i) {
                int row = sub*16 + quad*4 + i;
                int jd = jb + row;
                jd = jd < 0 ? 0 : jd;
                jd = jd > 256 ? 256 : jd;
                float ev = exp2f(s4[sub][i] + bf16f(sR[row][jd]));
                e[sub][i] = ev;
                lsum[sub][i] += ev;
                if (jd == 0)        slow[sub][i]  += ev;
                else if (jd == 256) shigh[sub][i] += ev;
                sP[buf][sub][quad*4 + i][w*16 + lq] = f2b(ev);
            }
        }
        if (needG) {
            #pragma unroll
            for (int i = 0; i < 7; ++i) {
                int idx = tid + i * 256;
                if (idx < 1664) ((unsigned int*)sG)[idx] = 0u;
            }
        }
        __syncthreads();

        if (needG) {
            #pragma unroll
            for (int sub = 0; sub < 2; ++sub) {
                int jminb = q0 + sub*16 - k0 - 63;
                jminb = (jminb < -127 ? -127 : jminb) + 128;
                int jlo8 = jminb & ~7;
                if (jlo8 > 160) jlo8 = 160;
                #pragma unroll
                for (int i = 0; i < 4; ++i) {
                    int jd = jb + sub*16 + quad*4 + i;   // interior: equals clamped jd
                    if (jd > 0 && jd < 256)
                        sG[sub][quad*4 + i][jd - jlo8] = f2b(e[sub][i]);
                }
            }
        }

        #pragma unroll
        for (int sub = 0; sub < 2; ++sub) {
            short8 ap0 = *(const short8*)&sP[buf][sub][lq][quad*8];
            short8 ap1 = *(const short8*)&sP[buf][sub][lq][32 + quad*8];
            c1a[sub] = __builtin_amdgcn_mfma_f32_16x16x32_bf16(ap0, cv0, c1a[sub], 0, 0, 0);
            c1a[sub] = __builtin_amdgcn_mfma_f32_16x16x32_bf16(ap1, cv1, c1a[sub], 0, 0, 0);
        }

        if (needG) {
            __syncthreads();
            #pragma unroll
            for (int sub = 0; sub < 2; ++sub) {
                int jminb = q0 + sub*16 - k0 - 63;
                jminb = (jminb < -127 ? -127 : jminb) + 128;
                int jlo8 = jminb & ~7;
                if (jlo8 > 160) jlo8 = 160;
                short8 ag0 = *(const short8*)&sG[sub][lq][quad*8];
                short8 ag1 = *(const short8*)&sG[sub][lq][32 + quad*8];
                short8 ag2 = *(const short8*)&sG[sub][lq][64 + quad*8];
                const unsigned short* rrow = relvT + (size_t)(w*16 + lq) * 264 + jlo8;
                short8 br0 = *(const short8*)(rrow + quad*8);
                short8 br1 = *(const short8*)(rrow + 32 + quad*8);
                short8 br2 = *(const short8*)(rrow + 64 + quad*8);
                c2a[sub] = __builtin_amdgcn_mfma_f32_16x16x32_bf16(ag0, br0, c2a[sub], 0, 0, 0);
                c2a[sub] = __builtin_amdgcn_mfma_f32_16x16x32_bf16(ag1, br1, c2a[sub], 0, 0, 0);
                c2a[sub] = __builtin_amdgcn_mfma_f32_16x16x32_bf16(ag2, br2, c2a[sub], 0, 0, 0);
            }
            __syncthreads();
        }

        ck0 = nk0; ck1 = nk1; cv0 = nv0; cv1 = nv1;
    }

    #pragma unroll
    for (int off = 1; off < 16; off <<= 1) {
        #pragma unroll
        for (int sub = 0; sub < 2; ++sub)
            #pragma unroll
            for (int i = 0; i < 4; ++i) {
                lsum[sub][i]  += __shfl_xor(lsum[sub][i],  off, 64);
                slow[sub][i]  += __shfl_xor(slow[sub][i],  off, 64);
                shigh[sub][i] += __shfl_xor(shigh[sub][i], off, 64);
            }
    }
    if (lq == 0) {
        #pragma unroll
        for (int sub = 0; sub < 2; ++sub)
            #pragma unroll
            for (int i = 0; i < 4; ++i) {
                int row = sub*16 + quad*4 + i;
                sRed[w][0][row] = lsum[sub][i];
                sRed[w][1][row] = slow[sub][i];
                sRed[w][2][row] = shigh[sub][i];
            }
    }
    __syncthreads();

    const int b1 = m >> 4,  h1 = m & 15;
    const int b2 = m2 >> 4, h2 = m2 & 15;
    #pragma unroll
    for (int sub = 0; sub < 2; ++sub) {
        #pragma unroll
        for (int i = 0; i < 4; ++i) {
            int row = sub*16 + quad*4 + i;
            float lt = sRed[0][0][row] + sRed[1][0][row] + sRed[2][0][row] + sRed[3][0][row];
            float sl = sRed[0][1][row] + sRed[1][1][row] + sRed[2][1][row] + sRed[3][1][row];
            float sh = sRed[0][2][row] + sRed[1][2][row] + sRed[2][2][row] + sRed[3][2][row];
            float c2v = c2a[sub][i] + sl * relE0 + sh * relE1;
            float inv = 1.0f / lt;
            int col = w*16 + lq;
            c1[(size_t)(b1*1024 + q0 + row) * 1024 + h1*64 + col] = c1a[sub][i] * inv;
            c2[(size_t)(b2*1024 + q0 + row) * 1024 + h2*64 + col] = c2v * inv;
        }
    }
}

// ---------------------------------------------------------------------------
// K2b: A = c1+c2 -> bf16 (hi,lo) split, written into the dead hh/hl buffers.
// ---------------------------------------------------------------------------
__global__ __launch_bounds__(256) void k_sum(
    const float* __restrict__ c1, const float* __restrict__ c2,
    unsigned short* __restrict__ ah, unsigned short* __restrict__ al)
{
    const int stride = gridDim.x * 256;
    for (int i = blockIdx.x * 256 + threadIdx.x; i < 1048576; i += stride) {
        float4 a = *(const float4*)(c1 + i*4);
        float4 b = *(const float4*)(c2 + i*4);
        float s[4] = {a.x+b.x, a.y+b.y, a.z+b.z, a.w+b.w};
        unsigned short h[4], l[4];
        #pragma unroll
        for (int j = 0; j < 4; ++j) {
            h[j] = f2b(s[j]);
            l[j] = f2b(s[j] - bf16f(h[j]));
        }
        *(ushort4*)(ah + i*4) = make_ushort4(h[0], h[1], h[2], h[3]);
        *(ushort4*)(al + i*4) = make_ushort4(l[0], l[1], l[2], l[3]);
    }
}

// ---------------------------------------------------------------------------
// K3: out = A @ Wo^T + bo with A = pre-split (c1+c2) hi/lo.  R24: 64x64
// tile, 1024 blocks = 4/CU (was 128x64, 512 blocks = 2/CU), LDS 32 KB,
// async dbuf staging, 3-MFMA (AhBh+AlBh+AhBl).  XCD swizzle same-nb.
// Per-output k-order identical to R21 -> bit-identical output.
// ---------------------------------------------------------------------------
__global__ __launch_bounds__(256, 4) void k_gemm_o(
    const unsigned short* __restrict__ ah_, const unsigned short* __restrict__ al_,
    const unsigned short* __restrict__ woh, const unsigned short* __restrict__ wol,
    const float* __restrict__ bo, float* __restrict__ outp)
{
    __shared__ __align__(16) unsigned short sAh[2][64][32];
    __shared__ __align__(16) unsigned short sAl[2][64][32];
    __shared__ __align__(16) unsigned short sBh[2][64][32];
    __shared__ __align__(16) unsigned short sBl[2][64][32];
    const int tid = threadIdx.x;
    // XCD-aware remap: 1024 blocks = 8 * 128, bijective
    const int d_ = blockIdx.x + (blockIdx.y << 4);
    const int l_ = (d_ & 7) * 128 + (d_ >> 3);
    const int eb = (l_ & 15) * 64, nb = (l_ >> 4) * 64;
    const int w = tid >> 6, lane = tid & 63, lq = lane & 15, quad = lane >> 4;
    const int wr = w >> 1, wc = w & 1;

    const int prow = lane >> 2;
    const int pc8  = ((((lane & 3) - ((lane >> 3) & 3)) & 3)) * 8;
    const int arow = nb + w*16 + prow;
    const int brow = eb + w*16 + prow;

    f32x4 acc[2][2];
    #pragma unroll
    for (int i = 0; i < 2; ++i)
        #pragma unroll
        for (int j = 0; j < 2; ++j) acc[i][j] = (f32x4){0,0,0,0};

    const int pcol = ((quad + (lq >> 1)) & 3) * 8;

    // prologue: stage tile 0 into buf 0
    {
        gl_lds16(ah_ + (size_t)arow * 1024 + pc8, &sAh[0][w*16][0]);
        gl_lds16(al_ + (size_t)arow * 1024 + pc8, &sAl[0][w*16][0]);
        gl_lds16(woh + (size_t)brow * 1024 + pc8, &sBh[0][w*16][0]);
        gl_lds16(wol + (size_t)brow * 1024 + pc8, &sBl[0][w*16][0]);
    }

    for (int k0 = 0; k0 < 1024; k0 += 32) {
        const int cur = (k0 >> 5) & 1;
        __syncthreads();
        if (k0 < 992) {
            const int kn = k0 + 32, nxt = 1 - cur;
            gl_lds16(ah_ + (size_t)arow * 1024 + kn + pc8, &sAh[nxt][w*16][0]);
            gl_lds16(al_ + (size_t)arow * 1024 + kn + pc8, &sAl[nxt][w*16][0]);
            gl_lds16(woh + (size_t)brow * 1024 + kn + pc8, &sBh[nxt][w*16][0]);
            gl_lds16(wol + (size_t)brow * 1024 + kn + pc8, &sBl[nxt][w*16][0]);
        }

        short8 ah[2], al[2], bhf[2], blf[2];
        #pragma unroll
        for (int t = 0; t < 2; ++t) {
            ah[t] = *(const short8*)&sAh[cur][wr*32 + t*16 + lq][pcol];
            al[t] = *(const short8*)&sAl[cur][wr*32 + t*16 + lq][pcol];
        }
        #pragma unroll
        for (int t = 0; t < 2; ++t) {
            bhf[t] = *(const short8*)&sBh[cur][wc*32 + t*16 + lq][pcol];
            blf[t] = *(const short8*)&sBl[cur][wc*32 + t*16 + lq][pcol];
        }
        #pragma unroll
        for (int ti = 0; ti < 2; ++ti)
            #pragma unroll
            for (int tj = 0; tj < 2; ++tj) {
                acc[ti][tj] = __builtin_amdgcn_mfma_f32_16x16x32_bf16(ah[ti], bhf[tj], acc[ti][tj], 0, 0, 0);
                acc[ti][tj] = __builtin_amdgcn_mfma_f32_16x16x32_bf16(al[ti], bhf[tj], acc[ti][tj], 0, 0, 0);
                acc[ti][tj] = __builtin_amdgcn_mfma_f32_16x16x32_bf16(ah[ti], blf[tj], acc[ti][tj], 0, 0, 0);
            }
    }

    #pragma unroll
    for (int tj = 0; tj < 2; ++tj) {
        int e = eb + wc*32 + tj*16 + lq;
        float bb = bo[e];
        #pragma unroll
        for (int ti = 0; ti < 2; ++ti) {
            #pragma unroll
            for (int i = 0; i < 4; ++i) {
                int n = nb + wr*32 + ti*16 + quad*4 + i;
                outp[(size_t)n * 1024 + e] = acc[ti][tj][i] + bb;
            }
        }
    }
}

// ---------------------------------------------------------------------------
extern "C" void kernel_launch(void* const* d_in, const int* in_sizes, int n_in,
                              void* d_out, int out_size, void* d_ws, size_t ws_size,
                              hipStream_t stream) {
    const float* hs   = (const float*)d_in[0];
    const float* Wq   = (const float*)d_in[1];
    const float* bq   = (const float*)d_in[2];
    const float* Wk   = (const float*)d_in[3];
    const float* bk   = (const float*)d_in[4];
    const float* Wv   = (const float*)d_in[5];
    const float* bv   = (const float*)d_in[6];
    const float* Wo   = (const float*)d_in[7];
    const float* bo   = (const float*)d_in[8];
    const float* relk = (const float*)d_in[9];
    const float* relv = (const float*)d_in[10];
    float* out = (float*)d_out;

    unsigned short* wsu = (unsigned short*)d_ws;
    unsigned short* qbp   = wsu;
    unsigned short* kbp   = wsu + 4194304;
    unsigned short* vtp   = wsu + 8388608;
    unsigned short* relkB = wsu + 12582912;
    unsigned short* relvT = wsu + 12600320;
    float* c1 = (float*)(wsu + 12617360);
    float* c2 = c1 + 4194304;
    unsigned short* hh  = wsu + 29394576;
    unsigned short* hl  = hh + 4194304;
    unsigned short* wqh = hl + 4194304;
    unsigned short* wql = wqh + 1048576;
    unsigned short* wkh = wql + 1048576;
    unsigned short* wkl = wkh + 1048576;
    unsigned short* wvh = wkl + 1048576;
    unsigned short* wvl = wvh + 1048576;
    unsigned short* woh = wvl + 1048576;
    unsigned short* wol = woh + 1048576;

    k_prep<<<dim3(512, 6), 256, 0, stream>>>(hs, Wq, Wk, Wv, Wo, relk, relv,
                                             hh, hl, wqh, wql, wkh, wkl,
                                             wvh, wvl, woh, wol, relkB, relvT);
    k_gemm_qkv<<<dim3(8, 32, 3), 256, 0, stream>>>(hh, hl, wqh, wkh, wvh,
                                                   bq, bk, bv, qbp, kbp, vtp);
    k_fused<<<dim3(32, 64), 256, 0, stream>>>(qbp, kbp, vtp, relkB, relvT, relv, c1, c2);
    // hh/hl are dead after k_gemm_qkv -> reuse as (c1+c2) hi/lo
    k_sum<<<dim3(2048), 256, 0, stream>>>(c1, c2, hh, hl);
    k_gemm_o<<<dim3(16, 64), 256, 0, stream>>>(hh, hl, woh, wol, bo, out);
}

// Round 10
// 363.469 us; speedup vs baseline: 1.3159x; 1.0125x over previous
//
#include <hip/hip_runtime.h>
#include <hip/hip_bf16.h>

// B=4, T=1024, E=1024, H=16, D=64, P=257.  Slot s = b*16+h (64 slots).
// Quirk: score slot m uses rel-K of slot pm=(m&15)*4+(m>>4); attn of slot m
// feeds w2 output of slot m2=(m&3)*16+(m>>2).
// R25: config = R21 (best, 366.3us; R24 gemm_o retile was neutral ->
// reverted).  One change: k_gemm_qkv swizzle nb-major -> z-major per XCD
// (for z {for nb_local(4) {for eb(8)}}): one z's whole B (2MB) + current A
// panel (0.5MB) stay L2-resident (was: 24 B-panels = 6MB > 4MB L2 cycling
// per nb-group -> B staging missed L2; vmcnt(0) drain ate L3/HBM latency
// every K-step).  Outputs bit-identical.
// R21: log2-domain softmax (Q pre-scaled 0.125*log2e), med3 jd clamp.
// R20: XCD swizzle.  R18/19: k_sum + qkv-clone k_gemm_o.  R16: qkv 128x128.

typedef __attribute__((ext_vector_type(8))) short short8;
typedef __attribute__((ext_vector_type(4))) float f32x4;

__device__ __forceinline__ float bf16f(unsigned int u) {
    union { unsigned int i; float f; } v; v.i = u << 16; return v.f;
}
__device__ __forceinline__ unsigned short f2b(float x) {
    __hip_bfloat16 h = __float2bfloat16(x);
    return *reinterpret_cast<unsigned short*>(&h);
}
__device__ __forceinline__ void gl_lds16(const unsigned short* g, unsigned short* l) {
    __builtin_amdgcn_global_load_lds(
        (const __attribute__((address_space(1))) void*)g,
        (__attribute__((address_space(3))) void*)l, 16, 0, 0);
}

// ---------------------------------------------------------------------------
// K0: prep.  z=0..4: split fp32 -> (hi,lo) bf16.  z=5: rel tables.
// lo halves skipped for Wq/Wk/Wv (z=1..3) - never read.
// ---------------------------------------------------------------------------
__global__ __launch_bounds__(256) void k_prep(
    const float* __restrict__ hs, const float* __restrict__ Wq,
    const float* __restrict__ Wk, const float* __restrict__ Wv,
    const float* __restrict__ Wo, const float* __restrict__ relk,
    const float* __restrict__ relv,
    unsigned short* __restrict__ hh, unsigned short* __restrict__ hl,
    unsigned short* __restrict__ wqh, unsigned short* __restrict__ wql,
    unsigned short* __restrict__ wkh, unsigned short* __restrict__ wkl,
    unsigned short* __restrict__ wvh, unsigned short* __restrict__ wvl,
    unsigned short* __restrict__ woh, unsigned short* __restrict__ wol,
    unsigned short* __restrict__ relkB, unsigned short* __restrict__ relvT)
{
    const int z = blockIdx.y;
    const int tid = threadIdx.x;
    if (z < 5) {
        const float* src = (z == 0) ? hs : (z == 1) ? Wq : (z == 2) ? Wk
                         : (z == 3) ? Wv : Wo;
        unsigned short* hi = (z == 0) ? hh : (z == 1) ? wqh : (z == 2) ? wkh
                           : (z == 3) ? wvh : woh;
        unsigned short* lo = (z == 0) ? hl : (z == 1) ? wql : (z == 2) ? wkl
                           : (z == 3) ? wvl : wol;
        const bool wlo = (z == 0) || (z == 4);
        const int n4 = (z == 0) ? 1048576 : 262144;
        const int stride = gridDim.x * 256;
        for (int i = blockIdx.x * 256 + tid; i < n4; i += stride) {
            float4 x = *(const float4*)(src + i*4);
            unsigned short h[4], l[4];
            float xs[4] = {x.x, x.y, x.z, x.w};
            #pragma unroll
            for (int j = 0; j < 4; ++j) {
                h[j] = f2b(xs[j]);
                l[j] = f2b(xs[j] - bf16f(h[j]));
            }
            *(ushort4*)(hi + i*4) = make_ushort4(h[0], h[1], h[2], h[3]);
            if (wlo)
                *(ushort4*)(lo + i*4) = make_ushort4(l[0], l[1], l[2], l[3]);
        }
    } else if (blockIdx.x == 0) {
        for (int i = tid; i < 272*64; i += 256) {
            int j = i >> 6;
            relkB[i] = (j < 257) ? f2b(relk[i]) : (unsigned short)0;
        }
        int d = tid >> 2, grp = tid & 3;
        for (int jj = 0; jj < 66; ++jj) {
            int j = grp*66 + jj;
            if (j < 264)
                relvT[d*264 + j] = (j < 257) ? f2b(relv[j*64 + d]) : (unsigned short)0;
        }
    }
}

// ---------------------------------------------------------------------------
// K1: QKV projection, 128x128 tile, double-buffered async staging, 2-MFMA
// split (AhBh + AlBh).  Grid (8, 32, 3) = 768 blocks = 3/CU, LDS 48 KB.
// R25: z-major per-XCD swizzle - B-z (2MB) L2-resident across 32 consecutive
// blocks, A panel (0.5MB) across 8.  R21: z==0 scale folds log2e.
// ---------------------------------------------------------------------------
__global__ __launch_bounds__(256, 3) void k_gemm_qkv(
    const unsigned short* __restrict__ hh, const unsigned short* __restrict__ hl,
    const unsigned short* __restrict__ wqh, const unsigned short* __restrict__ wkh,
    const unsigned short* __restrict__ wvh,
    const float* __restrict__ bq, const float* __restrict__ bk,
    const float* __restrict__ bv,
    unsigned short* __restrict__ qb, unsigned short* __restrict__ kb,
    unsigned short* __restrict__ vt)
{
    __shared__ __align__(16) unsigned short sAh[2][128][32];
    __shared__ __align__(16) unsigned short sAl[2][128][32];
    __shared__ __align__(16) unsigned short sBh[2][128][32];
    const int tid = threadIdx.x;
    // XCD-aware remap (768 = 8 XCD * 96, bijective), z-major within XCD:
    // xcd covers nb in {4*xcd..4*xcd+3}; order = for z {for nb_l {for eb}}.
    const int d_ = blockIdx.x + (blockIdx.y << 3) + (blockIdx.z << 8);
    const int xcd = d_ & 7;
    const int j_  = d_ >> 3;          // 0..95
    const int z   = j_ >> 5;          // 0..2
    const int r_  = j_ & 31;
    const int nbb = xcd * 4 + (r_ >> 3);
    const int ebb = r_ & 7;
    const int eb = ebb * 128, nb = nbb * 128;
    const unsigned short* Bh = (z == 0) ? wqh : (z == 1) ? wkh : wvh;
    const float* bias = (z == 0) ? bq : (z == 1) ? bk : bv;
    const float scale = (z == 0) ? 0.125f * 1.44269504f : 1.0f;
    const int w = tid >> 6, lane = tid & 63, lq = lane & 15, quad = lane >> 4;
    const int wr = w >> 1, wc = w & 1;

    const int prow = lane >> 2;
    const int pc8  = ((((lane & 3) - ((lane >> 3) & 3)) & 3)) * 8;
    const int arow = nb + w*16 + prow;
    const int brow = eb + w*16 + prow;

    f32x4 acc[4][4];
    #pragma unroll
    for (int i = 0; i < 4; ++i)
        #pragma unroll
        for (int j = 0; j < 4; ++j) acc[i][j] = (f32x4){0,0,0,0};

    const int pcol = ((quad + (lq >> 1)) & 3) * 8;   // swizzled frag column

    {
        gl_lds16(hh + (size_t)arow * 1024 + pc8,        &sAh[0][w*16][0]);
        gl_lds16(hh + (size_t)(arow + 64) * 1024 + pc8, &sAh[0][64 + w*16][0]);
        gl_lds16(hl + (size_t)arow * 1024 + pc8,        &sAl[0][w*16][0]);
        gl_lds16(hl + (size_t)(arow + 64) * 1024 + pc8, &sAl[0][64 + w*16][0]);
        gl_lds16(Bh + (size_t)brow * 1024 + pc8,        &sBh[0][w*16][0]);
        gl_lds16(Bh + (size_t)(brow + 64) * 1024 + pc8, &sBh[0][64 + w*16][0]);
    }

    for (int k0 = 0; k0 < 1024; k0 += 32) {
        const int cur = (k0 >> 5) & 1;
        __syncthreads();
        if (k0 < 992) {
            const int kn = k0 + 32, nxt = 1 - cur;
            gl_lds16(hh + (size_t)arow * 1024 + kn + pc8,        &sAh[nxt][w*16][0]);
            gl_lds16(hh + (size_t)(arow + 64) * 1024 + kn + pc8, &sAh[nxt][64 + w*16][0]);
            gl_lds16(hl + (size_t)arow * 1024 + kn + pc8,        &sAl[nxt][w*16][0]);
            gl_lds16(hl + (size_t)(arow + 64) * 1024 + kn + pc8, &sAl[nxt][64 + w*16][0]);
            gl_lds16(Bh + (size_t)brow * 1024 + kn + pc8,        &sBh[nxt][w*16][0]);
            gl_lds16(Bh + (size_t)(brow + 64) * 1024 + kn + pc8, &sBh[nxt][64 + w*16][0]);
        }

        short8 ah[4], al[4], bh4[4];
        #pragma unroll
        for (int t = 0; t < 4; ++t) {
            ah[t] = *(const short8*)&sAh[cur][wr*64 + t*16 + lq][pcol];
            al[t] = *(const short8*)&sAl[cur][wr*64 + t*16 + lq][pcol];
        }
        #pragma unroll
        for (int t = 0; t < 4; ++t)
            bh4[t] = *(const short8*)&sBh[cur][wc*64 + t*16 + lq][pcol];
        #pragma unroll
        for (int ti = 0; ti < 4; ++ti)
            #pragma unroll
            for (int tj = 0; tj < 4; ++tj) {
                acc[ti][tj] = __builtin_amdgcn_mfma_f32_16x16x32_bf16(ah[ti], bh4[tj], acc[ti][tj], 0, 0, 0);
                acc[ti][tj] = __builtin_amdgcn_mfma_f32_16x16x32_bf16(al[ti], bh4[tj], acc[ti][tj], 0, 0, 0);
            }
    }

    #pragma unroll
    for (int tj = 0; tj < 4; ++tj) {
        int e = eb + wc*64 + tj*16 + lq;
        float bb = bias[e];
        int h = e >> 6, d = e & 63;
        #pragma unroll
        for (int ti = 0; ti < 4; ++ti) {
            #pragma unroll
            for (int i = 0; i < 4; ++i) {
                int n = nb + wr*64 + ti*16 + quad*4 + i;
                int bidx = n >> 10, t = n & 1023;
                int s = bidx*16 + h;
                float val = (acc[ti][tj][i] + bb) * scale;
                if (z == 2)
                    vt[(((size_t)(s*64 + d)) << 10) + t] = f2b(val);
                else if (z == 0)
                    qb[(((size_t)(s*1024 + t)) << 6) + d] = f2b(val);
                else
                    kb[(((size_t)(s*1024 + t)) << 6) + d] = f2b(val);
            }
        }
    }
}

// ---------------------------------------------------------------------------
// K2: MFMA flash attention (verbatim R21).  log2-domain softmax + med3 jd
// clamp; XCD swizzle.  LDS 35.3 KB / VGPR 84 -> 4 blocks/CU (local optimum).
// ---------------------------------------------------------------------------
__global__ __launch_bounds__(256) void k_fused(
    const unsigned short* __restrict__ qb, const unsigned short* __restrict__ kb,
    const unsigned short* __restrict__ vt, const unsigned short* __restrict__ relkB,
    const unsigned short* __restrict__ relvT, const float* __restrict__ relv,
    float* __restrict__ c1, float* __restrict__ c2)
{
    __shared__ __align__(16) unsigned short sP[2][2][16][72];
    __shared__ __align__(16) unsigned short sG[2][16][104];
    __shared__ unsigned short sR[32][273];
    __shared__ float sRed[4][3][32];

    const int tid = threadIdx.x;
    // XCD-aware remap: 2048 blocks = 8 * 256, bijective
    const int d_ = blockIdx.x + (blockIdx.y << 5);
    const int l_ = (d_ & 7) * 256 + (d_ >> 3);
    const int m  = l_ >> 5;
    const int q0 = (l_ & 31) * 32;
    const int pm = (m & 15) * 4 + (m >> 4);
    const int m2 = (m & 3) * 16 + (m >> 2);
    const int w    = tid >> 6;
    const int lane = tid & 63;
    const int lq   = lane & 15;
    const int quad = lane >> 4;

    #pragma unroll
    for (int sub = 0; sub < 2; ++sub) {
        const unsigned short* qpm = qb + (((size_t)(pm*1024 + q0 + sub*16 + lq)) << 6);
        short8 a0 = *(const short8*)(qpm + quad*8);
        short8 a1 = *(const short8*)(qpm + 32 + quad*8);
        for (int jt = w; jt < 17; jt += 4) {
            const unsigned short* rkb = relkB + (size_t)(jt*16 + lq) * 64;
            short8 b0 = *(const short8*)(rkb + quad*8);
            short8 b1 = *(const short8*)(rkb + 32 + quad*8);
            f32x4 cr = {0,0,0,0};
            cr = __builtin_amdgcn_mfma_f32_16x16x32_bf16(a0, b0, cr, 0, 0, 0);
            cr = __builtin_amdgcn_mfma_f32_16x16x32_bf16(a1, b1, cr, 0, 0, 0);
            #pragma unroll
            for (int i = 0; i < 4; ++i)
                sR[sub*16 + quad*4 + i][jt*16 + lq] = f2b(cr[i]);
        }
    }
    __syncthreads();

    short8 aq0[2], aq1[2];
    #pragma unroll
    for (int sub = 0; sub < 2; ++sub) {
        const unsigned short* qm = qb + (((size_t)(m*1024 + q0 + sub*16 + lq)) << 6);
        aq0[sub] = *(const short8*)(qm + quad*8);
        aq1[sub] = *(const short8*)(qm + 32 + quad*8);
    }
    const float relE0 = relv[w*16 + lq];
    const float relE1 = relv[256*64 + w*16 + lq];

    float lsum[2][4], slow[2][4], shigh[2][4];
    f32x4 c1a[2], c2a[2];
    #pragma unroll
    for (int sub = 0; sub < 2; ++sub) {
        c1a[sub] = (f32x4){0,0,0,0};
        c2a[sub] = (f32x4){0,0,0,0};
        #pragma unroll
        for (int i = 0; i < 4; ++i) {
            lsum[sub][i] = 0.0f; slow[sub][i] = 0.0f; shigh[sub][i] = 0.0f;
        }
    }

    const unsigned short* kbase = kb + (((size_t)(m*1024 + w*16 + lq)) << 6);
    const unsigned short* vbase = vt + (((size_t)(m*64 + w*16 + lq)) << 10);
    short8 ck0 = *(const short8*)(kbase + quad*8);
    short8 ck1 = *(const short8*)(kbase + 32 + quad*8);
    short8 cv0 = *(const short8*)(vbase + quad*8);
    short8 cv1 = *(const short8*)(vbase + 32 + quad*8);

    // jd = clamp(jbase + row - 64*kt, 0, 256), row = sub*16+quad*4+i
    const int jbase = q0 + 128 - (w*16 + lq);

    #pragma unroll 1
    for (int kt = 0; kt < 16; ++kt) {
        const int k0 = kt * 64;
        const int dmin = q0 - k0 - 63;
        const int dmax = q0 + 31 - k0;
        const bool needG = (dmax >= -127) && (dmin <= 127);
        const int buf = kt & 1;
        const int jb = jbase - k0;

        short8 nk0 = ck0, nk1 = ck1, nv0 = cv0, nv1 = cv1;
        if (kt < 15) {
            const size_t ko = (size_t)(k0 + 64);
            nk0 = *(const short8*)(kbase + (ko << 6) + quad*8);
            nk1 = *(const short8*)(kbase + (ko << 6) + 32 + quad*8);
            nv0 = *(const short8*)(vbase + ko + quad*8);
            nv1 = *(const short8*)(vbase + ko + 32 + quad*8);
        }

        f32x4 s4[2];
        #pragma unroll
        for (int sub = 0; sub < 2; ++sub) {
            s4[sub] = (f32x4){0,0,0,0};
            s4[sub] = __builtin_amdgcn_mfma_f32_16x16x32_bf16(aq0[sub], ck0, s4[sub], 0, 0, 0);
            s4[sub] = __builtin_amdgcn_mfma_f32_16x16x32_bf16(aq1[sub], ck1, s4[sub], 0, 0, 0);
        }

        float e[2][4];
        #pragma unroll
        for (int sub = 0; sub < 2; ++sub) {
            #pragma unroll
            for (int i = 0; i < 4; ++i) {
                int row = sub*16 + quad*4 + i;
                int jd = jb + row;
                jd = jd < 0 ? 0 : jd;
                jd = jd > 256 ? 256 : jd;
                float ev = exp2f(s4[sub][i] + bf16f(sR[row][jd]));
                e[sub][i] = ev;
                lsum[sub][i] += ev;
                if (jd == 0)        slow[sub][i]  += ev;
                else if (jd == 256) shigh[sub][i] += ev;
                sP[buf][sub][quad*4 + i][w*16 + lq] = f2b(ev);
            }
        }
        if (needG) {
            #pragma unroll
            for (int i = 0; i < 7; ++i) {
                int idx = tid + i * 256;
                if (idx < 1664) ((unsigned int*)sG)[idx] = 0u;
            }
        }
        __syncthreads();

        if (needG) {
            #pragma unroll
            for (int sub = 0; sub < 2; ++sub) {
                int jminb = q0 + sub*16 - k0 - 63;
                jminb = (jminb < -127 ? -127 : jminb) + 128;
                int jlo8 = jminb & ~7;
                if (jlo8 > 160) jlo8 = 160;
                #pragma unroll
                for (int i = 0; i < 4; ++i) {
                    int jd = jb + sub*16 + quad*4 + i;   // interior: equals clamped jd
                    if (jd > 0 && jd < 256)
                        sG[sub][quad*4 + i][jd - jlo8] = f2b(e[sub][i]);
                }
            }
        }

        #pragma unroll
        for (int sub = 0; sub < 2; ++sub) {
            short8 ap0 = *(const short8*)&sP[buf][sub][lq][quad*8];
            short8 ap1 = *(const short8*)&sP[buf][sub][lq][32 + quad*8];
            c1a[sub] = __builtin_amdgcn_mfma_f32_16x16x32_bf16(ap0, cv0, c1a[sub], 0, 0, 0);
            c1a[sub] = __builtin_amdgcn_mfma_f32_16x16x32_bf16(ap1, cv1, c1a[sub], 0, 0, 0);
        }

        if (needG) {
            __syncthreads();
            #pragma unroll
            for (int sub = 0; sub < 2; ++sub) {
                int jminb = q0 + sub*16 - k0 - 63;
                jminb = (jminb < -127 ? -127 : jminb) + 128;
                int jlo8 = jminb & ~7;
                if (jlo8 > 160) jlo8 = 160;
                short8 ag0 = *(const short8*)&sG[sub][lq][quad*8];
                short8 ag1 = *(const short8*)&sG[sub][lq][32 + quad*8];
                short8 ag2 = *(const short8*)&sG[sub][lq][64 + quad*8];
                const unsigned short* rrow = relvT + (size_t)(w*16 + lq) * 264 + jlo8;
                short8 br0 = *(const short8*)(rrow + quad*8);
                short8 br1 = *(const short8*)(rrow + 32 + quad*8);
                short8 br2 = *(const short8*)(rrow + 64 + quad*8);
                c2a[sub] = __builtin_amdgcn_mfma_f32_16x16x32_bf16(ag0, br0, c2a[sub], 0, 0, 0);
                c2a[sub] = __builtin_amdgcn_mfma_f32_16x16x32_bf16(ag1, br1, c2a[sub], 0, 0, 0);
                c2a[sub] = __builtin_amdgcn_mfma_f32_16x16x32_bf16(ag2, br2, c2a[sub], 0, 0, 0);
            }
            __syncthreads();
        }

        ck0 = nk0; ck1 = nk1; cv0 = nv0; cv1 = nv1;
    }

    #pragma unroll
    for (int off = 1; off < 16; off <<= 1) {
        #pragma unroll
        for (int sub = 0; sub < 2; ++sub)
            #pragma unroll
            for (int i = 0; i < 4; ++i) {
                lsum[sub][i]  += __shfl_xor(lsum[sub][i],  off, 64);
                slow[sub][i]  += __shfl_xor(slow[sub][i],  off, 64);
                shigh[sub][i] += __shfl_xor(shigh[sub][i], off, 64);
            }
    }
    if (lq == 0) {
        #pragma unroll
        for (int sub = 0; sub < 2; ++sub)
            #pragma unroll
            for (int i = 0; i < 4; ++i) {
                int row = sub*16 + quad*4 + i;
                sRed[w][0][row] = lsum[sub][i];
                sRed[w][1][row] = slow[sub][i];
                sRed[w][2][row] = shigh[sub][i];
            }
    }
    __syncthreads();

    const int b1 = m >> 4,  h1 = m & 15;
    const int b2 = m2 >> 4, h2 = m2 & 15;
    #pragma unroll
    for (int sub = 0; sub < 2; ++sub) {
        #pragma unroll
        for (int i = 0; i < 4; ++i) {
            int row = sub*16 + quad*4 + i;
            float lt = sRed[0][0][row] + sRed[1][0][row] + sRed[2][0][row] + sRed[3][0][row];
            float sl = sRed[0][1][row] + sRed[1][1][row] + sRed[2][1][row] + sRed[3][1][row];
            float sh = sRed[0][2][row] + sRed[1][2][row] + sRed[2][2][row] + sRed[3][2][row];
            float c2v = c2a[sub][i] + sl * relE0 + sh * relE1;
            float inv = 1.0f / lt;
            int col = w*16 + lq;
            c1[(size_t)(b1*1024 + q0 + row) * 1024 + h1*64 + col] = c1a[sub][i] * inv;
            c2[(size_t)(b2*1024 + q0 + row) * 1024 + h2*64 + col] = c2v * inv;
        }
    }
}

// ---------------------------------------------------------------------------
// K2b: A = c1+c2 -> bf16 (hi,lo) split, written into the dead hh/hl buffers.
// ---------------------------------------------------------------------------
__global__ __launch_bounds__(256) void k_sum(
    const float* __restrict__ c1, const float* __restrict__ c2,
    unsigned short* __restrict__ ah, unsigned short* __restrict__ al)
{
    const int stride = gridDim.x * 256;
    for (int i = blockIdx.x * 256 + threadIdx.x; i < 1048576; i += stride) {
        float4 a = *(const float4*)(c1 + i*4);
        float4 b = *(const float4*)(c2 + i*4);
        float s[4] = {a.x+b.x, a.y+b.y, a.z+b.z, a.w+b.w};
        unsigned short h[4], l[4];
        #pragma unroll
        for (int j = 0; j < 4; ++j) {
            h[j] = f2b(s[j]);
            l[j] = f2b(s[j] - bf16f(h[j]));
        }
        *(ushort4*)(ah + i*4) = make_ushort4(h[0], h[1], h[2], h[3]);
        *(ushort4*)(al + i*4) = make_ushort4(l[0], l[1], l[2], l[3]);
    }
}

// ---------------------------------------------------------------------------
// K3: out = A @ Wo^T + bo with A = pre-split (c1+c2) hi/lo.  qkv-clone:
// 128x64 tile, cross-iteration async dbuf staging, 3-MFMA (AhBh+AlBh+AhBl).
// Grid (16,32) = 512 blocks, LDS 48 KB.  R20: XCD swizzle, same-nb (16
// eb-blocks, shared A-panel) contiguous per XCD.  (verbatim R21)
// ---------------------------------------------------------------------------
__global__ __launch_bounds__(256, 3) void k_gemm_o(
    const unsigned short* __restrict__ ah_, const unsigned short* __restrict__ al_,
    const unsigned short* __restrict__ woh, const unsigned short* __restrict__ wol,
    const float* __restrict__ bo, float* __restrict__ outp)
{
    __shared__ __align__(16) unsigned short sAh[2][128][32];
    __shared__ __align__(16) unsigned short sAl[2][128][32];
    __shared__ __align__(16) unsigned short sBh[2][64][32];
    __shared__ __align__(16) unsigned short sBl[2][64][32];
    const int tid = threadIdx.x;
    // XCD-aware remap: 512 blocks = 8 * 64, bijective
    const int d_ = blockIdx.x + (blockIdx.y << 4);
    const int l_ = (d_ & 7) * 64 + (d_ >> 3);
    const int eb = (l_ & 15) * 64, nb = (l_ >> 4) * 128;
    const int w = tid >> 6, lane = tid & 63, lq = lane & 15, quad = lane >> 4;
    const int wr = w >> 1, wc = w & 1;

    const int prow = lane >> 2;
    const int pc8  = ((((lane & 3) - ((lane >> 3) & 3)) & 3)) * 8;
    const int arow = nb + w*16 + prow;
    const int brow = eb + w*16 + prow;

    f32x4 acc[4][2];
    #pragma unroll
    for (int i = 0; i < 4; ++i)
        #pragma unroll
        for (int j = 0; j < 2; ++j) acc[i][j] = (f32x4){0,0,0,0};

    const int pcol = ((quad + (lq >> 1)) & 3) * 8;

    // prologue: stage tile 0 into buf 0
    {
        gl_lds16(ah_ + (size_t)arow * 1024 + pc8,        &sAh[0][w*16][0]);
        gl_lds16(ah_ + (size_t)(arow + 64) * 1024 + pc8, &sAh[0][64 + w*16][0]);
        gl_lds16(al_ + (size_t)arow * 1024 + pc8,        &sAl[0][w*16][0]);
        gl_lds16(al_ + (size_t)(arow + 64) * 1024 + pc8, &sAl[0][64 + w*16][0]);
        gl_lds16(woh + (size_t)brow * 1024 + pc8,        &sBh[0][w*16][0]);
        gl_lds16(wol + (size_t)brow * 1024 + pc8,        &sBl[0][w*16][0]);
    }

    for (int k0 = 0; k0 < 1024; k0 += 32) {
        const int cur = (k0 >> 5) & 1;
        __syncthreads();
        if (k0 < 992) {
            const int kn = k0 + 32, nxt = 1 - cur;
            gl_lds16(ah_ + (size_t)arow * 1024 + kn + pc8,        &sAh[nxt][w*16][0]);
            gl_lds16(ah_ + (size_t)(arow + 64) * 1024 + kn + pc8, &sAh[nxt][64 + w*16][0]);
            gl_lds16(al_ + (size_t)arow * 1024 + kn + pc8,        &sAl[nxt][w*16][0]);
            gl_lds16(al_ + (size_t)(arow + 64) * 1024 + kn + pc8, &sAl[nxt][64 + w*16][0]);
            gl_lds16(woh + (size_t)brow * 1024 + kn + pc8,        &sBh[nxt][w*16][0]);
            gl_lds16(wol + (size_t)brow * 1024 + kn + pc8,        &sBl[nxt][w*16][0]);
        }

        short8 ah[4], al[4], bhf[2], blf[2];
        #pragma unroll
        for (int t = 0; t < 4; ++t) {
            ah[t] = *(const short8*)&sAh[cur][wr*64 + t*16 + lq][pcol];
            al[t] = *(const short8*)&sAl[cur][wr*64 + t*16 + lq][pcol];
        }
        #pragma unroll
        for (int t = 0; t < 2; ++t) {
            bhf[t] = *(const short8*)&sBh[cur][wc*32 + t*16 + lq][pcol];
            blf[t] = *(const short8*)&sBl[cur][wc*32 + t*16 + lq][pcol];
        }
        #pragma unroll
        for (int ti = 0; ti < 4; ++ti)
            #pragma unroll
            for (int tj = 0; tj < 2; ++tj) {
                acc[ti][tj] = __builtin_amdgcn_mfma_f32_16x16x32_bf16(ah[ti], bhf[tj], acc[ti][tj], 0, 0, 0);
                acc[ti][tj] = __builtin_amdgcn_mfma_f32_16x16x32_bf16(al[ti], bhf[tj], acc[ti][tj], 0, 0, 0);
                acc[ti][tj] = __builtin_amdgcn_mfma_f32_16x16x32_bf16(ah[ti], blf[tj], acc[ti][tj], 0, 0, 0);
            }
    }

    #pragma unroll
    for (int tj = 0; tj < 2; ++tj) {
        int e = eb + wc*32 + tj*16 + lq;
        float bb = bo[e];
        #pragma unroll
        for (int ti = 0; ti < 4; ++ti) {
            #pragma unroll
            for (int i = 0; i < 4; ++i) {
                int n = nb + wr*64 + ti*16 + quad*4 + i;
                outp[(size_t)n * 1024 + e] = acc[ti][tj][i] + bb;
            }
        }
    }
}

// ---------------------------------------------------------------------------
extern "C" void kernel_launch(void* const* d_in, const int* in_sizes, int n_in,
                              void* d_out, int out_size, void* d_ws, size_t ws_size,
                              hipStream_t stream) {
    const float* hs   = (const float*)d_in[0];
    const float* Wq   = (const float*)d_in[1];
    const float* bq   = (const float*)d_in[2];
    const float* Wk   = (const float*)d_in[3];
    const float* bk   = (const float*)d_in[4];
    const float* Wv   = (const float*)d_in[5];
    const float* bv   = (const float*)d_in[6];
    const float* Wo   = (const float*)d_in[7];
    const float* bo   = (const float*)d_in[8];
    const float* relk = (const float*)d_in[9];
    const float* relv = (const float*)d_in[10];
    float* out = (float*)d_out;

    unsigned short* wsu = (unsigned short*)d_ws;
    unsigned short* qbp   = wsu;
    unsigned short* kbp   = wsu + 4194304;
    unsigned short* vtp   = wsu + 8388608;
    unsigned short* relkB = wsu + 12582912;
    unsigned short* relvT = wsu + 12600320;
    float* c1 = (float*)(wsu + 12617360);
    float* c2 = c1 + 4194304;
    unsigned short* hh  = wsu + 29394576;
    unsigned short* hl  = hh + 4194304;
    unsigned short* wqh = hl + 4194304;
    unsigned short* wql = wqh + 1048576;
    unsigned short* wkh = wql + 1048576;
    unsigned short* wkl = wkh + 1048576;
    unsigned short* wvh = wkl + 1048576;
    unsigned short* wvl = wvh + 1048576;
    unsigned short* woh = wvl + 1048576;
    unsigned short* wol = woh + 1048576;

    k_prep<<<dim3(512, 6), 256, 0, stream>>>(hs, Wq, Wk, Wv, Wo, relk, relv,
                                             hh, hl, wqh, wql, wkh, wkl,
                                             wvh, wvl, woh, wol, relkB, relvT);
    k_gemm_qkv<<<dim3(8, 32, 3), 256, 0, stream>>>(hh, hl, wqh, wkh, wvh,
                                                   bq, bk, bv, qbp, kbp, vtp);
    k_fused<<<dim3(32, 64), 256, 0, stream>>>(qbp, kbp, vtp, relkB, relvT, relv, c1, c2);
    // hh/hl are dead after k_gemm_qkv -> reuse as (c1+c2) hi/lo
    k_sum<<<dim3(2048), 256, 0, stream>>>(c1, c2, hh, hl);
    k_gemm_o<<<dim3(16, 32), 256, 0, stream>>>(hh, hl, woh, wol, bo, out);
}

// Round 11
// 361.048 us; speedup vs baseline: 1.3247x; 1.0067x over previous
//
#include <hip/hip_runtime.h>
#include <hip/hip_bf16.h>

// B=4, T=1024, E=1024, H=16, D=64, P=257.  Slot s = b*16+h (64 slots).
// Quirk: score slot m uses rel-K of slot pm=(m&15)*4+(m>>4); attn of slot m
// feeds w2 output of slot m2=(m&3)*16+(m>>2).
// R26: k_fused LDS diet 35.3K -> ~32.3K to fit 5 blocks/CU (was 4; LDS was
// the sole occupancy limiter - VGPR 84 allows 6 waves/SIMD).  (a) sR
// [32][273]->[32][257] (only cols 0..256 read; jt=16 prologue store guarded
// col<257), (b) sRed aliased onto sP (kt15 mid-barrier orders kt14's sP[0]
// reads before epilogue writes; existing syncthreads before sRed reads).
// Loop body, barriers, tile, registers untouched (R16-family pure-residency
// move).  Downside bounded: if alloc rounds >32768 -> 4 blocks = R25 exact.
// R25: qkv z-major swizzle.  R21: log2-domain softmax, med3 clamp.
// R20: XCD swizzle.  R18/19: k_sum + qkv-clone k_gemm_o.  R16: qkv 128x128.

typedef __attribute__((ext_vector_type(8))) short short8;
typedef __attribute__((ext_vector_type(4))) float f32x4;

__device__ __forceinline__ float bf16f(unsigned int u) {
    union { unsigned int i; float f; } v; v.i = u << 16; return v.f;
}
__device__ __forceinline__ unsigned short f2b(float x) {
    __hip_bfloat16 h = __float2bfloat16(x);
    return *reinterpret_cast<unsigned short*>(&h);
}
__device__ __forceinline__ void gl_lds16(const unsigned short* g, unsigned short* l) {
    __builtin_amdgcn_global_load_lds(
        (const __attribute__((address_space(1))) void*)g,
        (__attribute__((address_space(3))) void*)l, 16, 0, 0);
}

// ---------------------------------------------------------------------------
// K0: prep.  z=0..4: split fp32 -> (hi,lo) bf16.  z=5: rel tables.
// lo halves skipped for Wq/Wk/Wv (z=1..3) - never read.
// ---------------------------------------------------------------------------
__global__ __launch_bounds__(256) void k_prep(
    const float* __restrict__ hs, const float* __restrict__ Wq,
    const float* __restrict__ Wk, const float* __restrict__ Wv,
    const float* __restrict__ Wo, const float* __restrict__ relk,
    const float* __restrict__ relv,
    unsigned short* __restrict__ hh, unsigned short* __restrict__ hl,
    unsigned short* __restrict__ wqh, unsigned short* __restrict__ wql,
    unsigned short* __restrict__ wkh, unsigned short* __restrict__ wkl,
    unsigned short* __restrict__ wvh, unsigned short* __restrict__ wvl,
    unsigned short* __restrict__ woh, unsigned short* __restrict__ wol,
    unsigned short* __restrict__ relkB, unsigned short* __restrict__ relvT)
{
    const int z = blockIdx.y;
    const int tid = threadIdx.x;
    if (z < 5) {
        const float* src = (z == 0) ? hs : (z == 1) ? Wq : (z == 2) ? Wk
                         : (z == 3) ? Wv : Wo;
        unsigned short* hi = (z == 0) ? hh : (z == 1) ? wqh : (z == 2) ? wkh
                           : (z == 3) ? wvh : woh;
        unsigned short* lo = (z == 0) ? hl : (z == 1) ? wql : (z == 2) ? wkl
                           : (z == 3) ? wvl : wol;
        const bool wlo = (z == 0) || (z == 4);
        const int n4 = (z == 0) ? 1048576 : 262144;
        const int stride = gridDim.x * 256;
        for (int i = blockIdx.x * 256 + tid; i < n4; i += stride) {
            float4 x = *(const float4*)(src + i*4);
            unsigned short h[4], l[4];
            float xs[4] = {x.x, x.y, x.z, x.w};
            #pragma unroll
            for (int j = 0; j < 4; ++j) {
                h[j] = f2b(xs[j]);
                l[j] = f2b(xs[j] - bf16f(h[j]));
            }
            *(ushort4*)(hi + i*4) = make_ushort4(h[0], h[1], h[2], h[3]);
            if (wlo)
                *(ushort4*)(lo + i*4) = make_ushort4(l[0], l[1], l[2], l[3]);
        }
    } else if (blockIdx.x == 0) {
        for (int i = tid; i < 272*64; i += 256) {
            int j = i >> 6;
            relkB[i] = (j < 257) ? f2b(relk[i]) : (unsigned short)0;
        }
        int d = tid >> 2, grp = tid & 3;
        for (int jj = 0; jj < 66; ++jj) {
            int j = grp*66 + jj;
            if (j < 264)
                relvT[d*264 + j] = (j < 257) ? f2b(relv[j*64 + d]) : (unsigned short)0;
        }
    }
}

// ---------------------------------------------------------------------------
// K1: QKV projection, 128x128 tile, double-buffered async staging, 2-MFMA
// split (AhBh + AlBh).  Grid (8, 32, 3) = 768 blocks = 3/CU, LDS 48 KB.
// R25: z-major per-XCD swizzle.  R21: z==0 scale folds log2e.
// ---------------------------------------------------------------------------
__global__ __launch_bounds__(256, 3) void k_gemm_qkv(
    const unsigned short* __restrict__ hh, const unsigned short* __restrict__ hl,
    const unsigned short* __restrict__ wqh, const unsigned short* __restrict__ wkh,
    const unsigned short* __restrict__ wvh,
    const float* __restrict__ bq, const float* __restrict__ bk,
    const float* __restrict__ bv,
    unsigned short* __restrict__ qb, unsigned short* __restrict__ kb,
    unsigned short* __restrict__ vt)
{
    __shared__ __align__(16) unsigned short sAh[2][128][32];
    __shared__ __align__(16) unsigned short sAl[2][128][32];
    __shared__ __align__(16) unsigned short sBh[2][128][32];
    const int tid = threadIdx.x;
    // XCD-aware remap (768 = 8 XCD * 96, bijective), z-major within XCD:
    // xcd covers nb in {4*xcd..4*xcd+3}; order = for z {for nb_l {for eb}}.
    const int d_ = blockIdx.x + (blockIdx.y << 3) + (blockIdx.z << 8);
    const int xcd = d_ & 7;
    const int j_  = d_ >> 3;          // 0..95
    const int z   = j_ >> 5;          // 0..2
    const int r_  = j_ & 31;
    const int nbb = xcd * 4 + (r_ >> 3);
    const int ebb = r_ & 7;
    const int eb = ebb * 128, nb = nbb * 128;
    const unsigned short* Bh = (z == 0) ? wqh : (z == 1) ? wkh : wvh;
    const float* bias = (z == 0) ? bq : (z == 1) ? bk : bv;
    const float scale = (z == 0) ? 0.125f * 1.44269504f : 1.0f;
    const int w = tid >> 6, lane = tid & 63, lq = lane & 15, quad = lane >> 4;
    const int wr = w >> 1, wc = w & 1;

    const int prow = lane >> 2;
    const int pc8  = ((((lane & 3) - ((lane >> 3) & 3)) & 3)) * 8;
    const int arow = nb + w*16 + prow;
    const int brow = eb + w*16 + prow;

    f32x4 acc[4][4];
    #pragma unroll
    for (int i = 0; i < 4; ++i)
        #pragma unroll
        for (int j = 0; j < 4; ++j) acc[i][j] = (f32x4){0,0,0,0};

    const int pcol = ((quad + (lq >> 1)) & 3) * 8;   // swizzled frag column

    {
        gl_lds16(hh + (size_t)arow * 1024 + pc8,        &sAh[0][w*16][0]);
        gl_lds16(hh + (size_t)(arow + 64) * 1024 + pc8, &sAh[0][64 + w*16][0]);
        gl_lds16(hl + (size_t)arow * 1024 + pc8,        &sAl[0][w*16][0]);
        gl_lds16(hl + (size_t)(arow + 64) * 1024 + pc8, &sAl[0][64 + w*16][0]);
        gl_lds16(Bh + (size_t)brow * 1024 + pc8,        &sBh[0][w*16][0]);
        gl_lds16(Bh + (size_t)(brow + 64) * 1024 + pc8, &sBh[0][64 + w*16][0]);
    }

    for (int k0 = 0; k0 < 1024; k0 += 32) {
        const int cur = (k0 >> 5) & 1;
        __syncthreads();
        if (k0 < 992) {
            const int kn = k0 + 32, nxt = 1 - cur;
            gl_lds16(hh + (size_t)arow * 1024 + kn + pc8,        &sAh[nxt][w*16][0]);
            gl_lds16(hh + (size_t)(arow + 64) * 1024 + kn + pc8, &sAh[nxt][64 + w*16][0]);
            gl_lds16(hl + (size_t)arow * 1024 + kn + pc8,        &sAl[nxt][w*16][0]);
            gl_lds16(hl + (size_t)(arow + 64) * 1024 + kn + pc8, &sAl[nxt][64 + w*16][0]);
            gl_lds16(Bh + (size_t)brow * 1024 + kn + pc8,        &sBh[nxt][w*16][0]);
            gl_lds16(Bh + (size_t)(brow + 64) * 1024 + kn + pc8, &sBh[nxt][64 + w*16][0]);
        }

        short8 ah[4], al[4], bh4[4];
        #pragma unroll
        for (int t = 0; t < 4; ++t) {
            ah[t] = *(const short8*)&sAh[cur][wr*64 + t*16 + lq][pcol];
            al[t] = *(const short8*)&sAl[cur][wr*64 + t*16 + lq][pcol];
        }
        #pragma unroll
        for (int t = 0; t < 4; ++t)
            bh4[t] = *(const short8*)&sBh[cur][wc*64 + t*16 + lq][pcol];
        #pragma unroll
        for (int ti = 0; ti < 4; ++ti)
            #pragma unroll
            for (int tj = 0; tj < 4; ++tj) {
                acc[ti][tj] = __builtin_amdgcn_mfma_f32_16x16x32_bf16(ah[ti], bh4[tj], acc[ti][tj], 0, 0, 0);
                acc[ti][tj] = __builtin_amdgcn_mfma_f32_16x16x32_bf16(al[ti], bh4[tj], acc[ti][tj], 0, 0, 0);
            }
    }

    #pragma unroll
    for (int tj = 0; tj < 4; ++tj) {
        int e = eb + wc*64 + tj*16 + lq;
        float bb = bias[e];
        int h = e >> 6, d = e & 63;
        #pragma unroll
        for (int ti = 0; ti < 4; ++ti) {
            #pragma unroll
            for (int i = 0; i < 4; ++i) {
                int n = nb + wr*64 + ti*16 + quad*4 + i;
                int bidx = n >> 10, t = n & 1023;
                int s = bidx*16 + h;
                float val = (acc[ti][tj][i] + bb) * scale;
                if (z == 2)
                    vt[(((size_t)(s*64 + d)) << 10) + t] = f2b(val);
                else if (z == 0)
                    qb[(((size_t)(s*1024 + t)) << 6) + d] = f2b(val);
                else
                    kb[(((size_t)(s*1024 + t)) << 6) + d] = f2b(val);
            }
        }
    }
}

// ---------------------------------------------------------------------------
// K2: MFMA flash attention (R21 structure).  R26: sR[32][257] + sRed aliased
// onto sP -> LDS ~32.3 KB -> 5 blocks/CU.  log2-domain softmax + med3 jd
// clamp; XCD swizzle.
// ---------------------------------------------------------------------------
__global__ __launch_bounds__(256) void k_fused(
    const unsigned short* __restrict__ qb, const unsigned short* __restrict__ kb,
    const unsigned short* __restrict__ vt, const unsigned short* __restrict__ relkB,
    const unsigned short* __restrict__ relvT, const float* __restrict__ relv,
    float* __restrict__ c1, float* __restrict__ c2)
{
    __shared__ __align__(16) unsigned short sP[2][2][16][72];
    __shared__ __align__(16) unsigned short sG[2][16][104];
    __shared__ __align__(16) unsigned short sR[32][257];
    // sRed[4][3][32] fp32 aliased onto sP (epilogue-only; see ordering note)
    float* sRedf = (float*)&sP[0][0][0][0];

    const int tid = threadIdx.x;
    // XCD-aware remap: 2048 blocks = 8 * 256, bijective
    const int d_ = blockIdx.x + (blockIdx.y << 5);
    const int l_ = (d_ & 7) * 256 + (d_ >> 3);
    const int m  = l_ >> 5;
    const int q0 = (l_ & 31) * 32;
    const int pm = (m & 15) * 4 + (m >> 4);
    const int m2 = (m & 3) * 16 + (m >> 2);
    const int w    = tid >> 6;
    const int lane = tid & 63;
    const int lq   = lane & 15;
    const int quad = lane >> 4;

    #pragma unroll
    for (int sub = 0; sub < 2; ++sub) {
        const unsigned short* qpm = qb + (((size_t)(pm*1024 + q0 + sub*16 + lq)) << 6);
        short8 a0 = *(const short8*)(qpm + quad*8);
        short8 a1 = *(const short8*)(qpm + 32 + quad*8);
        for (int jt = w; jt < 17; jt += 4) {
            const unsigned short* rkb = relkB + (size_t)(jt*16 + lq) * 64;
            short8 b0 = *(const short8*)(rkb + quad*8);
            short8 b1 = *(const short8*)(rkb + 32 + quad*8);
            f32x4 cr = {0,0,0,0};
            cr = __builtin_amdgcn_mfma_f32_16x16x32_bf16(a0, b0, cr, 0, 0, 0);
            cr = __builtin_amdgcn_mfma_f32_16x16x32_bf16(a1, b1, cr, 0, 0, 0);
            const int col = jt*16 + lq;
            if (col < 257) {
                #pragma unroll
                for (int i = 0; i < 4; ++i)
                    sR[sub*16 + quad*4 + i][col] = f2b(cr[i]);
            }
        }
    }
    __syncthreads();

    short8 aq0[2], aq1[2];
    #pragma unroll
    for (int sub = 0; sub < 2; ++sub) {
        const unsigned short* qm = qb + (((size_t)(m*1024 + q0 + sub*16 + lq)) << 6);
        aq0[sub] = *(const short8*)(qm + quad*8);
        aq1[sub] = *(const short8*)(qm + 32 + quad*8);
    }
    const float relE0 = relv[w*16 + lq];
    const float relE1 = relv[256*64 + w*16 + lq];

    float lsum[2][4], slow[2][4], shigh[2][4];
    f32x4 c1a[2], c2a[2];
    #pragma unroll
    for (int sub = 0; sub < 2; ++sub) {
        c1a[sub] = (f32x4){0,0,0,0};
        c2a[sub] = (f32x4){0,0,0,0};
        #pragma unroll
        for (int i = 0; i < 4; ++i) {
            lsum[sub][i] = 0.0f; slow[sub][i] = 0.0f; shigh[sub][i] = 0.0f;
        }
    }

    const unsigned short* kbase = kb + (((size_t)(m*1024 + w*16 + lq)) << 6);
    const unsigned short* vbase = vt + (((size_t)(m*64 + w*16 + lq)) << 10);
    short8 ck0 = *(const short8*)(kbase + quad*8);
    short8 ck1 = *(const short8*)(kbase + 32 + quad*8);
    short8 cv0 = *(const short8*)(vbase + quad*8);
    short8 cv1 = *(const short8*)(vbase + 32 + quad*8);

    // jd = clamp(jbase + row - 64*kt, 0, 256), row = sub*16+quad*4+i
    const int jbase = q0 + 128 - (w*16 + lq);

    #pragma unroll 1
    for (int kt = 0; kt < 16; ++kt) {
        const int k0 = kt * 64;
        const int dmin = q0 - k0 - 63;
        const int dmax = q0 + 31 - k0;
        const bool needG = (dmax >= -127) && (dmin <= 127);
        const int buf = kt & 1;
        const int jb = jbase - k0;

        short8 nk0 = ck0, nk1 = ck1, nv0 = cv0, nv1 = cv1;
        if (kt < 15) {
            const size_t ko = (size_t)(k0 + 64);
            nk0 = *(const short8*)(kbase + (ko << 6) + quad*8);
            nk1 = *(const short8*)(kbase + (ko << 6) + 32 + quad*8);
            nv0 = *(const short8*)(vbase + ko + quad*8);
            nv1 = *(const short8*)(vbase + ko + 32 + quad*8);
        }

        f32x4 s4[2];
        #pragma unroll
        for (int sub = 0; sub < 2; ++sub) {
            s4[sub] = (f32x4){0,0,0,0};
            s4[sub] = __builtin_amdgcn_mfma_f32_16x16x32_bf16(aq0[sub], ck0, s4[sub], 0, 0, 0);
            s4[sub] = __builtin_amdgcn_mfma_f32_16x16x32_bf16(aq1[sub], ck1, s4[sub], 0, 0, 0);
        }

        float e[2][4];
        #pragma unroll
        for (int sub = 0; sub < 2; ++sub) {
            #pragma unroll
            for (int i = 0; i < 4; ++i) {
                int row = sub*16 + quad*4 + i;
                int jd = jb + row;
                jd = jd < 0 ? 0 : jd;
                jd = jd > 256 ? 256 : jd;
                float ev = exp2f(s4[sub][i] + bf16f(sR[row][jd]));
                e[sub][i] = ev;
                lsum[sub][i] += ev;
                if (jd == 0)        slow[sub][i]  += ev;
                else if (jd == 256) shigh[sub][i] += ev;
                sP[buf][sub][quad*4 + i][w*16 + lq] = f2b(ev);
            }
        }
        if (needG) {
            #pragma unroll
            for (int i = 0; i < 7; ++i) {
                int idx = tid + i * 256;
                if (idx < 1664) ((unsigned int*)sG)[idx] = 0u;
            }
        }
        __syncthreads();

        if (needG) {
            #pragma unroll
            for (int sub = 0; sub < 2; ++sub) {
                int jminb = q0 + sub*16 - k0 - 63;
                jminb = (jminb < -127 ? -127 : jminb) + 128;
                int jlo8 = jminb & ~7;
                if (jlo8 > 160) jlo8 = 160;
                #pragma unroll
                for (int i = 0; i < 4; ++i) {
                    int jd = jb + sub*16 + quad*4 + i;   // interior: equals clamped jd
                    if (jd > 0 && jd < 256)
                        sG[sub][quad*4 + i][jd - jlo8] = f2b(e[sub][i]);
                }
            }
        }

        #pragma unroll
        for (int sub = 0; sub < 2; ++sub) {
            short8 ap0 = *(const short8*)&sP[buf][sub][lq][quad*8];
            short8 ap1 = *(const short8*)&sP[buf][sub][lq][32 + quad*8];
            c1a[sub] = __builtin_amdgcn_mfma_f32_16x16x32_bf16(ap0, cv0, c1a[sub], 0, 0, 0);
            c1a[sub] = __builtin_amdgcn_mfma_f32_16x16x32_bf16(ap1, cv1, c1a[sub], 0, 0, 0);
        }

        if (needG) {
            __syncthreads();
            #pragma unroll
            for (int sub = 0; sub < 2; ++sub) {
                int jminb = q0 + sub*16 - k0 - 63;
                jminb = (jminb < -127 ? -127 : jminb) + 128;
                int jlo8 = jminb & ~7;
                if (jlo8 > 160) jlo8 = 160;
                short8 ag0 = *(const short8*)&sG[sub][lq][quad*8];
                short8 ag1 = *(const short8*)&sG[sub][lq][32 + quad*8];
                short8 ag2 = *(const short8*)&sG[sub][lq][64 + quad*8];
                const unsigned short* rrow = relvT + (size_t)(w*16 + lq) * 264 + jlo8;
                short8 br0 = *(const short8*)(rrow + quad*8);
                short8 br1 = *(const short8*)(rrow + 32 + quad*8);
                short8 br2 = *(const short8*)(rrow + 64 + quad*8);
                c2a[sub] = __builtin_amdgcn_mfma_f32_16x16x32_bf16(ag0, br0, c2a[sub], 0, 0, 0);
                c2a[sub] = __builtin_amdgcn_mfma_f32_16x16x32_bf16(ag1, br1, c2a[sub], 0, 0, 0);
                c2a[sub] = __builtin_amdgcn_mfma_f32_16x16x32_bf16(ag2, br2, c2a[sub], 0, 0, 0);
            }
            __syncthreads();
        }

        ck0 = nk0; ck1 = nk1; cv0 = nv0; cv1 = nv1;
    }

    #pragma unroll
    for (int off = 1; off < 16; off <<= 1) {
        #pragma unroll
        for (int sub = 0; sub < 2; ++sub)
            #pragma unroll
            for (int i = 0; i < 4; ++i) {
                lsum[sub][i]  += __shfl_xor(lsum[sub][i],  off, 64);
                slow[sub][i]  += __shfl_xor(slow[sub][i],  off, 64);
                shigh[sub][i] += __shfl_xor(shigh[sub][i], off, 64);
            }
    }
    // sRedf aliases sP[0..1535B]; kt15's mid-barrier ordered kt14's sP[0]
    // reads before this point, and kt15's PV reads touch only sP[1].
    if (lq == 0) {
        #pragma unroll
        for (int sub = 0; sub < 2; ++sub)
            #pragma unroll
            for (int i = 0; i < 4; ++i) {
                int row = sub*16 + quad*4 + i;
                sRedf[w*96 + 0*32 + row] = lsum[sub][i];
                sRedf[w*96 + 1*32 + row] = slow[sub][i];
                sRedf[w*96 + 2*32 + row] = shigh[sub][i];
            }
    }
    __syncthreads();

    const int b1 = m >> 4,  h1 = m & 15;
    const int b2 = m2 >> 4, h2 = m2 & 15;
    #pragma unroll
    for (int sub = 0; sub < 2; ++sub) {
        #pragma unroll
        for (int i = 0; i < 4; ++i) {
            int row = sub*16 + quad*4 + i;
            float lt = sRedf[0*96 + row] + sRedf[1*96 + row] + sRedf[2*96 + row] + sRedf[3*96 + row];
            float sl = sRedf[0*96 + 32 + row] + sRedf[1*96 + 32 + row] + sRedf[2*96 + 32 + row] + sRedf[3*96 + 32 + row];
            float sh = sRedf[0*96 + 64 + row] + sRedf[1*96 + 64 + row] + sRedf[2*96 + 64 + row] + sRedf[3*96 + 64 + row];
            float c2v = c2a[sub][i] + sl * relE0 + sh * relE1;
            float inv = 1.0f / lt;
            int col = w*16 + lq;
            c1[(size_t)(b1*1024 + q0 + row) * 1024 + h1*64 + col] = c1a[sub][i] * inv;
            c2[(size_t)(b2*1024 + q0 + row) * 1024 + h2*64 + col] = c2v * inv;
        }
    }
}

// ---------------------------------------------------------------------------
// K2b: A = c1+c2 -> bf16 (hi,lo) split, written into the dead hh/hl buffers.
// ---------------------------------------------------------------------------
__global__ __launch_bounds__(256) void k_sum(
    const float* __restrict__ c1, const float* __restrict__ c2,
    unsigned short* __restrict__ ah, unsigned short* __restrict__ al)
{
    const int stride = gridDim.x * 256;
    for (int i = blockIdx.x * 256 + threadIdx.x; i < 1048576; i += stride) {
        float4 a = *(const float4*)(c1 + i*4);
        float4 b = *(const float4*)(c2 + i*4);
        float s[4] = {a.x+b.x, a.y+b.y, a.z+b.z, a.w+b.w};
        unsigned short h[4], l[4];
        #pragma unroll
        for (int j = 0; j < 4; ++j) {
            h[j] = f2b(s[j]);
            l[j] = f2b(s[j] - bf16f(h[j]));
        }
        *(ushort4*)(ah + i*4) = make_ushort4(h[0], h[1], h[2], h[3]);
        *(ushort4*)(al + i*4) = make_ushort4(l[0], l[1], l[2], l[3]);
    }
}

// ---------------------------------------------------------------------------
// K3: out = A @ Wo^T + bo with A = pre-split (c1+c2) hi/lo.  qkv-clone:
// 128x64 tile, cross-iteration async dbuf staging, 3-MFMA (AhBh+AlBh+AhBl).
// Grid (16,32) = 512 blocks, LDS 48 KB.  R20: XCD swizzle, same-nb (16
// eb-blocks, shared A-panel) contiguous per XCD.  (verbatim R21)
// ---------------------------------------------------------------------------
__global__ __launch_bounds__(256, 3) void k_gemm_o(
    const unsigned short* __restrict__ ah_, const unsigned short* __restrict__ al_,
    const unsigned short* __restrict__ woh, const unsigned short* __restrict__ wol,
    const float* __restrict__ bo, float* __restrict__ outp)
{
    __shared__ __align__(16) unsigned short sAh[2][128][32];
    __shared__ __align__(16) unsigned short sAl[2][128][32];
    __shared__ __align__(16) unsigned short sBh[2][64][32];
    __shared__ __align__(16) unsigned short sBl[2][64][32];
    const int tid = threadIdx.x;
    // XCD-aware remap: 512 blocks = 8 * 64, bijective
    const int d_ = blockIdx.x + (blockIdx.y << 4);
    const int l_ = (d_ & 7) * 64 + (d_ >> 3);
    const int eb = (l_ & 15) * 64, nb = (l_ >> 4) * 128;
    const int w = tid >> 6, lane = tid & 63, lq = lane & 15, quad = lane >> 4;
    const int wr = w >> 1, wc = w & 1;

    const int prow = lane >> 2;
    const int pc8  = ((((lane & 3) - ((lane >> 3) & 3)) & 3)) * 8;
    const int arow = nb + w*16 + prow;
    const int brow = eb + w*16 + prow;

    f32x4 acc[4][2];
    #pragma unroll
    for (int i = 0; i < 4; ++i)
        #pragma unroll
        for (int j = 0; j < 2; ++j) acc[i][j] = (f32x4){0,0,0,0};

    const int pcol = ((quad + (lq >> 1)) & 3) * 8;

    // prologue: stage tile 0 into buf 0
    {
        gl_lds16(ah_ + (size_t)arow * 1024 + pc8,        &sAh[0][w*16][0]);
        gl_lds16(ah_ + (size_t)(arow + 64) * 1024 + pc8, &sAh[0][64 + w*16][0]);
        gl_lds16(al_ + (size_t)arow * 1024 + pc8,        &sAl[0][w*16][0]);
        gl_lds16(al_ + (size_t)(arow + 64) * 1024 + pc8, &sAl[0][64 + w*16][0]);
        gl_lds16(woh + (size_t)brow * 1024 + pc8,        &sBh[0][w*16][0]);
        gl_lds16(wol + (size_t)brow * 1024 + pc8,        &sBl[0][w*16][0]);
    }

    for (int k0 = 0; k0 < 1024; k0 += 32) {
        const int cur = (k0 >> 5) & 1;
        __syncthreads();
        if (k0 < 992) {
            const int kn = k0 + 32, nxt = 1 - cur;
            gl_lds16(ah_ + (size_t)arow * 1024 + kn + pc8,        &sAh[nxt][w*16][0]);
            gl_lds16(ah_ + (size_t)(arow + 64) * 1024 + kn + pc8, &sAh[nxt][64 + w*16][0]);
            gl_lds16(al_ + (size_t)arow * 1024 + kn + pc8,        &sAl[nxt][w*16][0]);
            gl_lds16(al_ + (size_t)(arow + 64) * 1024 + kn + pc8, &sAl[nxt][64 + w*16][0]);
            gl_lds16(woh + (size_t)brow * 1024 + kn + pc8,        &sBh[nxt][w*16][0]);
            gl_lds16(wol + (size_t)brow * 1024 + kn + pc8,        &sBl[nxt][w*16][0]);
        }

        short8 ah[4], al[4], bhf[2], blf[2];
        #pragma unroll
        for (int t = 0; t < 4; ++t) {
            ah[t] = *(const short8*)&sAh[cur][wr*64 + t*16 + lq][pcol];
            al[t] = *(const short8*)&sAl[cur][wr*64 + t*16 + lq][pcol];
        }
        #pragma unroll
        for (int t = 0; t < 2; ++t) {
            bhf[t] = *(const short8*)&sBh[cur][wc*32 + t*16 + lq][pcol];
            blf[t] = *(const short8*)&sBl[cur][wc*32 + t*16 + lq][pcol];
        }
        #pragma unroll
        for (int ti = 0; ti < 4; ++ti)
            #pragma unroll
            for (int tj = 0; tj < 2; ++tj) {
                acc[ti][tj] = __builtin_amdgcn_mfma_f32_16x16x32_bf16(ah[ti], bhf[tj], acc[ti][tj], 0, 0, 0);
                acc[ti][tj] = __builtin_amdgcn_mfma_f32_16x16x32_bf16(al[ti], bhf[tj], acc[ti][tj], 0, 0, 0);
                acc[ti][tj] = __builtin_amdgcn_mfma_f32_16x16x32_bf16(ah[ti], blf[tj], acc[ti][tj], 0, 0, 0);
            }
    }

    #pragma unroll
    for (int tj = 0; tj < 2; ++tj) {
        int e = eb + wc*32 + tj*16 + lq;
        float bb = bo[e];
        #pragma unroll
        for (int ti = 0; ti < 4; ++ti) {
            #pragma unroll
            for (int i = 0; i < 4; ++i) {
                int n = nb + wr*64 + ti*16 + quad*4 + i;
                outp[(size_t)n * 1024 + e] = acc[ti][tj][i] + bb;
            }
        }
    }
}

// ---------------------------------------------------------------------------
extern "C" void kernel_launch(void* const* d_in, const int* in_sizes, int n_in,
                              void* d_out, int out_size, void* d_ws, size_t ws_size,
                              hipStream_t stream) {
    const float* hs   = (const float*)d_in[0];
    const float* Wq   = (const float*)d_in[1];
    const float* bq   = (const float*)d_in[2];
    const float* Wk   = (const float*)d_in[3];
    const float* bk   = (const float*)d_in[4];
    const float* Wv   = (const float*)d_in[5];
    const float* bv   = (const float*)d_in[6];
    const float* Wo   = (const float*)d_in[7];
    const float* bo   = (const float*)d_in[8];
    const float* relk = (const float*)d_in[9];
    const float* relv = (const float*)d_in[10];
    float* out = (float*)d_out;

    unsigned short* wsu = (unsigned short*)d_ws;
    unsigned short* qbp   = wsu;
    unsigned short* kbp   = wsu + 4194304;
    unsigned short* vtp   = wsu + 8388608;
    unsigned short* relkB = wsu + 12582912;
    unsigned short* relvT = wsu + 12600320;
    float* c1 = (float*)(wsu + 12617360);
    float* c2 = c1 + 4194304;
    unsigned short* hh  = wsu + 29394576;
    unsigned short* hl  = hh + 4194304;
    unsigned short* wqh = hl + 4194304;
    unsigned short* wql = wqh + 1048576;
    unsigned short* wkh = wql + 1048576;
    unsigned short* wkl = wkh + 1048576;
    unsigned short* wvh = wkl + 1048576;
    unsigned short* wvl = wvh + 1048576;
    unsigned short* woh = wvl + 1048576;
    unsigned short* wol = woh + 1048576;

    k_prep<<<dim3(512, 6), 256, 0, stream>>>(hs, Wq, Wk, Wv, Wo, relk, relv,
                                             hh, hl, wqh, wql, wkh, wkl,
                                             wvh, wvl, woh, wol, relkB, relvT);
    k_gemm_qkv<<<dim3(8, 32, 3), 256, 0, stream>>>(hh, hl, wqh, wkh, wvh,
                                                   bq, bk, bv, qbp, kbp, vtp);
    k_fused<<<dim3(32, 64), 256, 0, stream>>>(qbp, kbp, vtp, relkB, relvT, relv, c1, c2);
    // hh/hl are dead after k_gemm_qkv -> reuse as (c1+c2) hi/lo
    k_sum<<<dim3(2048), 256, 0, stream>>>(c1, c2, hh, hl);
    k_gemm_o<<<dim3(16, 32), 256, 0, stream>>>(hh, hl, woh, wol, bo, out);
}